// Round 3
// baseline (1031.315 us; speedup 1.0000x reference)
//
#include <hip/hip_runtime.h>
#include <hip/hip_bf16.h>

#define C1 128   // heads1(4) * hid(32)
#define C2 64    // out channels layer 2

__device__ __forceinline__ float lrelu(float v) { return v > 0.f ? v : 0.2f * v; }

// dual-dtype input load: bf==true -> bf16, else fp32
__device__ __forceinline__ float ldin(const void* p, size_t i, bool bf) {
    return bf ? (float)((const __hip_bfloat16*)p)[i] : ((const float*)p)[i];
}

// storage-type helpers (h1/g2 may be fp32 or bf16 depending on ws_size)
__device__ __forceinline__ float ldf(const float* p) { return *p; }
__device__ __forceinline__ float ldf(const __hip_bfloat16* p) { return (float)*p; }
__device__ __forceinline__ void stf(float* p, float v) { *p = v; }
__device__ __forceinline__ void stf(__hip_bfloat16* p, float v) { *p = __float2bfloat16(v); }

// ---------------- dtype detection ----------------
// Look at low 16 bits of the first `nwords` 32-bit words of x. In a packed-bf16
// stream these are genuine bf16 data values (biased exponent ~[110,140] for
// N(0,1) data). In an fp32 stream they are low mantissa bits (~uniform ->
// ~12% in window). flag=1 -> bf16 inputs, flag=0 -> fp32 inputs.
__global__ __launch_bounds__(256)
void detect_kernel(const unsigned* __restrict__ xw, int nwords, int* __restrict__ flag) {
    __shared__ int cnt;
    if (threadIdx.x == 0) cnt = 0;
    __syncthreads();
    int my = 0;
    for (int i = threadIdx.x; i < nwords; i += 256) {
        unsigned lo = xw[i] & 0xFFFFu;
        int e = (lo >> 7) & 0xFF;
        if (e >= 110 && e <= 140) ++my;
    }
    atomicAdd(&cnt, my);
    __syncthreads();
    if (threadIdx.x == 0) *flag = (cnt * 2 > nwords) ? 1 : 0;
}

// ---------------- Layer 1 GEMM (x[N,128] @ W1[128,128]) + alpha dots ----------------
template <typename HT>
__global__ __launch_bounds__(128)
void gemm1_kernel(const void* __restrict__ x,
                  const void* __restrict__ W1,
                  const void* __restrict__ a_src,
                  const void* __restrict__ a_dst,
                  HT* __restrict__ h1,
                  float* __restrict__ as1,
                  float* __restrict__ ad1,
                  int N, const int* __restrict__ dflag) {
    const bool bf = (*dflag != 0);
    __shared__ float xs[8][C1];
    const int t = threadIdx.x;
    const int n0 = blockIdx.x * 8;
#pragma unroll
    for (int j = 0; j < 8; ++j) {
        int n = n0 + j;
        xs[j][t] = (n < N) ? ldin(x, (size_t)n * C1 + t, bf) : 0.f;
    }
    __syncthreads();
    float acc[8] = {0.f,0.f,0.f,0.f,0.f,0.f,0.f,0.f};
    if (bf) {
        const __hip_bfloat16* W = (const __hip_bfloat16*)W1;
        for (int k = 0; k < 128; ++k) {
            float wv = (float)W[k * C1 + t];
#pragma unroll
            for (int j = 0; j < 8; ++j) acc[j] += xs[j][k] * wv;
        }
    } else {
        const float* W = (const float*)W1;
        for (int k = 0; k < 128; ++k) {
            float wv = W[k * C1 + t];
#pragma unroll
            for (int j = 0; j < 8; ++j) acc[j] += xs[j][k] * wv;
        }
    }
    const float asv = ldin(a_src, t, bf);   // a_src1 flat [4*32] == column t
    const float adv = ldin(a_dst, t, bf);
    const int head = t >> 5;
#pragma unroll
    for (int j = 0; j < 8; ++j) {
        int n = n0 + j;
        if (n < N) stf(&h1[(size_t)n * C1 + t], acc[j]);
        float ps = acc[j] * asv;
        float pd = acc[j] * adv;
#pragma unroll
        for (int o = 16; o >= 1; o >>= 1) {
            ps += __shfl_xor(ps, o, 32);
            pd += __shfl_xor(pd, o, 32);
        }
        if ((t & 31) == 0 && n < N) {
            as1[n * 4 + head] = ps;
            ad1[n * 4 + head] = pd;
        }
    }
}

// ---------------- Layer 1 softmax denominator ----------------
__global__ __launch_bounds__(256)
void edge_denom1_kernel(const int* __restrict__ ei,
                        const float* __restrict__ as1,
                        const float* __restrict__ ad1,
                        float* __restrict__ denom1,
                        int N, int E) {
    for (int e = blockIdx.x * blockDim.x + threadIdx.x; e < E;
         e += gridDim.x * blockDim.x) {
        int s = ei[e], d = ei[E + e];
        if ((unsigned)s >= (unsigned)N || (unsigned)d >= (unsigned)N) continue;
#pragma unroll
        for (int h = 0; h < 4; ++h) {
            float w = expf(lrelu(as1[s * 4 + h] + ad1[d * 4 + h]));
            atomicAdd(&denom1[d * 4 + h], w);
        }
    }
}

// ---------------- Layer 1 message scatter ----------------
template <typename HT>
__global__ __launch_bounds__(256)
void msg1_kernel(const int* __restrict__ ei,
                 const HT* __restrict__ h1,
                 const float* __restrict__ as1,
                 const float* __restrict__ ad1,
                 const float* __restrict__ denom1,
                 float* __restrict__ out1,
                 int N, int E) {
    const long total = (long)E * C1;
    const long stride = (long)gridDim.x * blockDim.x;
    for (long i = (long)blockIdx.x * blockDim.x + threadIdx.x; i < total; i += stride) {
        int e = (int)(i >> 7);
        int c = (int)(i & 127);
        int s = ei[e], d = ei[E + e];
        if ((unsigned)s >= (unsigned)N || (unsigned)d >= (unsigned)N) continue;
        int h = c >> 5;
        float ev = lrelu(as1[s * 4 + h] + ad1[d * 4 + h]);
        float w = expf(ev) / denom1[d * 4 + h];
        atomicAdd(&out1[(size_t)d * C1 + c], ldf(&h1[(size_t)s * C1 + c]) * w);
    }
}

// ---------------- ELU(out1 + b1) in place ----------------
__global__ __launch_bounds__(256)
void elu_bias_kernel(float* __restrict__ out1,
                     const void* __restrict__ b1,
                     long total, const int* __restrict__ dflag) {
    const bool bf = (*dflag != 0);
    const long stride = (long)gridDim.x * blockDim.x;
    for (long i = (long)blockIdx.x * blockDim.x + threadIdx.x; i < total; i += stride) {
        float v = out1[i] + ldin(b1, i & 127, bf);
        out1[i] = v > 0.f ? v : expm1f(v);
    }
}

// ---------------- Layer 2 GEMM (h2[N,128] @ W2[128,64]) + alpha dots ----------------
template <typename HT>
__global__ __launch_bounds__(64)
void gemm2_kernel(const float* __restrict__ h2,
                  const void* __restrict__ W2,
                  const void* __restrict__ a_src,
                  const void* __restrict__ a_dst,
                  HT* __restrict__ g2,
                  float* __restrict__ as2,
                  float* __restrict__ ad2,
                  int N, const int* __restrict__ dflag) {
    const bool bf = (*dflag != 0);
    __shared__ float xs[8][C1];
    const int t = threadIdx.x;
    const int n0 = blockIdx.x * 8;
#pragma unroll
    for (int j = 0; j < 8; ++j) {
        int n = n0 + j;
        if (n < N) {
            xs[j][t]      = h2[(size_t)n * C1 + t];
            xs[j][t + 64] = h2[(size_t)n * C1 + t + 64];
        } else {
            xs[j][t] = 0.f; xs[j][t + 64] = 0.f;
        }
    }
    __syncthreads();
    float acc[8] = {0.f,0.f,0.f,0.f,0.f,0.f,0.f,0.f};
    if (bf) {
        const __hip_bfloat16* W = (const __hip_bfloat16*)W2;
        for (int k = 0; k < 128; ++k) {
            float wv = (float)W[k * C2 + t];
#pragma unroll
            for (int j = 0; j < 8; ++j) acc[j] += xs[j][k] * wv;
        }
    } else {
        const float* W = (const float*)W2;
        for (int k = 0; k < 128; ++k) {
            float wv = W[k * C2 + t];
#pragma unroll
            for (int j = 0; j < 8; ++j) acc[j] += xs[j][k] * wv;
        }
    }
    const float asv = ldin(a_src, t, bf);
    const float adv = ldin(a_dst, t, bf);
#pragma unroll
    for (int j = 0; j < 8; ++j) {
        int n = n0 + j;
        if (n < N) stf(&g2[(size_t)n * C2 + t], acc[j]);
        float ps = acc[j] * asv;
        float pd = acc[j] * adv;
#pragma unroll
        for (int o = 32; o >= 1; o >>= 1) {
            ps += __shfl_xor(ps, o, 64);
            pd += __shfl_xor(pd, o, 64);
        }
        if (t == 0 && n < N) {
            as2[n] = ps;
            ad2[n] = pd;
        }
    }
}

// ---------------- Layer 2 softmax denominator ----------------
__global__ __launch_bounds__(256)
void edge_denom2_kernel(const int* __restrict__ ei,
                        const float* __restrict__ as2,
                        const float* __restrict__ ad2,
                        float* __restrict__ denom2,
                        int N, int E) {
    for (int e = blockIdx.x * blockDim.x + threadIdx.x; e < E;
         e += gridDim.x * blockDim.x) {
        int s = ei[e], d = ei[E + e];
        if ((unsigned)s >= (unsigned)N || (unsigned)d >= (unsigned)N) continue;
        atomicAdd(&denom2[d], expf(lrelu(as2[s] + ad2[d])));
    }
}

// ---------------- Layer 2 message scatter ----------------
template <typename HT>
__global__ __launch_bounds__(256)
void msg2_kernel(const int* __restrict__ ei,
                 const HT* __restrict__ g2,
                 const float* __restrict__ as2,
                 const float* __restrict__ ad2,
                 const float* __restrict__ denom2,
                 float* __restrict__ out2,
                 int N, int E) {
    const long total = (long)E * C2;
    const long stride = (long)gridDim.x * blockDim.x;
    for (long i = (long)blockIdx.x * blockDim.x + threadIdx.x; i < total; i += stride) {
        int e = (int)(i >> 6);
        int c = (int)(i & 63);
        int s = ei[e], d = ei[E + e];
        if ((unsigned)s >= (unsigned)N || (unsigned)d >= (unsigned)N) continue;
        float ev = lrelu(as2[s] + ad2[d]);
        float w = expf(ev) / denom2[d];
        atomicAdd(&out2[(size_t)d * C2 + c], ldf(&g2[(size_t)s * C2 + c]) * w);
    }
}

// ---------------- Final bias + store (bf16 or fp32 per flag) ----------------
__global__ __launch_bounds__(256)
void out_kernel(const float* __restrict__ out2,
                const void* __restrict__ b2,
                void* __restrict__ y,
                long total, const int* __restrict__ dflag) {
    const bool bf = (*dflag != 0);
    const long stride = (long)gridDim.x * blockDim.x;
    for (long i = (long)blockIdx.x * blockDim.x + threadIdx.x; i < total; i += stride) {
        float v = out2[i] + ldin(b2, i & 63, bf);
        if (bf) ((__hip_bfloat16*)y)[i] = __float2bfloat16(v);
        else    ((float*)y)[i] = v;
    }
}

extern "C" void kernel_launch(void* const* d_in, const int* in_sizes, int n_in,
                              void* d_out, int out_size, void* d_ws, size_t ws_size,
                              hipStream_t stream) {
    const void* x    = d_in[0];
    const int*  ei   = (const int*)d_in[1];
    const void* W1   = d_in[2];
    const void* a_s1 = d_in[3];
    const void* a_d1 = d_in[4];
    const void* b1   = d_in[5];
    const void* W2   = d_in[6];
    const void* a_s2 = d_in[7];
    const void* a_d2 = d_in[8];
    const void* b2   = d_in[9];

    const int N = in_sizes[0] / C1;
    const int E = in_sizes[1] / 2;

    auto align16 = [](size_t v) { return (v + 15) & ~(size_t)15; };
    const size_t RF  = 16;                                  // dtype flag
    const size_t R1A = align16((size_t)N * C1 * 4);         // fp32 h/g
    const size_t R1B = align16((size_t)N * C1 * 2);         // bf16 h/g fallback
    const size_t R2  = align16((size_t)N * 8 * 4);          // as1+ad1 (reused as as2+ad2)
    const size_t R3  = align16((size_t)N * 4 * 4);          // denom1 (reused as denom2)
    const size_t R4  = align16((size_t)N * C1 * 4);         // out1 (reused as out2)
    const size_t needA = RF + R1A + R2 + R3 + R4;
    const bool planA = (ws_size >= needA);

    char* base = (char*)d_ws;
    int*  dflag = (int*)base;
    char* R1p = base + RF;
    char* R2p = R1p + (planA ? R1A : R1B);
    char* R3p = R2p + R2;
    char* R4p = R3p + R3;

    float* as1    = (float*)R2p;               // N*4
    float* ad1    = as1 + (size_t)N * 4;       // N*4
    float* denom1 = (float*)R3p;               // N*4
    float* out1   = (float*)R4p;               // N*C1
    float* as2    = (float*)R2p;               // N  (as1/ad1 dead by then)
    float* ad2    = as2 + N;                   // N
    float* denom2 = (float*)R3p;               // N
    float* out2   = (float*)R4p;               // N*C2 (out1 dead after gemm2)

    const int nb_nodes = (N + 7) / 8;

    detect_kernel<<<1, 256, 0, stream>>>((const unsigned*)x, 2048, dflag);
    // zero denom1 + out1 (contiguous R3..R4)
    hipMemsetAsync(R3p, 0, R3 + R4, stream);

    if (planA) {
        float* h1 = (float*)R1p;
        float* g2 = (float*)R1p;
        gemm1_kernel<float><<<nb_nodes, 128, 0, stream>>>(x, W1, a_s1, a_d1, h1, as1, ad1, N, dflag);
        edge_denom1_kernel<<<2048, 256, 0, stream>>>(ei, as1, ad1, denom1, N, E);
        msg1_kernel<float><<<32768, 256, 0, stream>>>(ei, h1, as1, ad1, denom1, out1, N, E);
        elu_bias_kernel<<<8192, 256, 0, stream>>>(out1, b1, (long)N * C1, dflag);
        gemm2_kernel<float><<<nb_nodes, 64, 0, stream>>>(out1, W2, a_s2, a_d2, g2, as2, ad2, N, dflag);
        hipMemsetAsync(R3p, 0, (size_t)N * 4, stream);          // denom2
        hipMemsetAsync(R4p, 0, (size_t)N * C2 * 4, stream);     // out2
        edge_denom2_kernel<<<2048, 256, 0, stream>>>(ei, as2, ad2, denom2, N, E);
        msg2_kernel<float><<<16384, 256, 0, stream>>>(ei, g2, as2, ad2, denom2, out2, N, E);
        out_kernel<<<4096, 256, 0, stream>>>(out2, b2, d_out, (long)N * C2, dflag);
    } else {
        __hip_bfloat16* h1 = (__hip_bfloat16*)R1p;
        __hip_bfloat16* g2 = (__hip_bfloat16*)R1p;
        gemm1_kernel<__hip_bfloat16><<<nb_nodes, 128, 0, stream>>>(x, W1, a_s1, a_d1, h1, as1, ad1, N, dflag);
        edge_denom1_kernel<<<2048, 256, 0, stream>>>(ei, as1, ad1, denom1, N, E);
        msg1_kernel<__hip_bfloat16><<<32768, 256, 0, stream>>>(ei, h1, as1, ad1, denom1, out1, N, E);
        elu_bias_kernel<<<8192, 256, 0, stream>>>(out1, b1, (long)N * C1, dflag);
        gemm2_kernel<__hip_bfloat16><<<nb_nodes, 64, 0, stream>>>(out1, W2, a_s2, a_d2, g2, as2, ad2, N, dflag);
        hipMemsetAsync(R3p, 0, (size_t)N * 4, stream);          // denom2
        hipMemsetAsync(R4p, 0, (size_t)N * C2 * 4, stream);     // out2
        edge_denom2_kernel<<<2048, 256, 0, stream>>>(ei, as2, ad2, denom2, N, E);
        msg2_kernel<__hip_bfloat16><<<16384, 256, 0, stream>>>(ei, g2, as2, ad2, denom2, out2, N, E);
        out_kernel<<<4096, 256, 0, stream>>>(out2, b2, d_out, (long)N * C2, dflag);
    }
}

// Round 4
// 503.604 us; speedup vs baseline: 2.0479x; 2.0479x over previous
//
#include <hip/hip_runtime.h>
#include <hip/hip_bf16.h>

#define C1 128   // heads1(4) * hid(32)
#define C2 64    // out channels layer 2

__device__ __forceinline__ float lrelu(float v) { return v > 0.f ? v : 0.2f * v; }

// dual-dtype input load: bf==true -> bf16, else fp32
__device__ __forceinline__ float ldin(const void* p, size_t i, bool bf) {
    return bf ? (float)((const __hip_bfloat16*)p)[i] : ((const float*)p)[i];
}

// ---------------- dtype detection (bf16 vs fp32 inputs) ----------------
__global__ __launch_bounds__(256)
void detect_kernel(const unsigned* __restrict__ xw, int nwords, int* __restrict__ flag) {
    __shared__ int cnt;
    if (threadIdx.x == 0) cnt = 0;
    __syncthreads();
    int my = 0;
    for (int i = threadIdx.x; i < nwords; i += 256) {
        unsigned lo = xw[i] & 0xFFFFu;
        int e = (lo >> 7) & 0xFF;
        if (e >= 110 && e <= 140) ++my;
    }
    atomicAdd(&cnt, my);
    __syncthreads();
    if (threadIdx.x == 0) *flag = (cnt * 2 > nwords) ? 1 : 0;
}

// ---------------- CSR build ----------------
__global__ __launch_bounds__(256)
void count_kernel(const int* __restrict__ ei, int* __restrict__ deg, int N, int E) {
    for (int e = blockIdx.x * blockDim.x + threadIdx.x; e < E;
         e += gridDim.x * blockDim.x) {
        int d = ei[E + e];
        if ((unsigned)d < (unsigned)N) atomicAdd(&deg[d], 1);
    }
}

// single-block exclusive scan: offs[i] = sum deg[0..i), offs[N] = total.
// also rewrites cursor[i] = offs[i] for the fill pass.
__global__ __launch_bounds__(1024)
void scan_kernel(const int* __restrict__ deg, int* __restrict__ offs,
                 int* __restrict__ cursor, int N) {
    __shared__ int wsum[16];
    __shared__ int carry_s;
    if (threadIdx.x == 0) carry_s = 0;
    __syncthreads();
    const int lane = threadIdx.x & 63;
    const int wid = threadIdx.x >> 6;
    for (int base = 0; base < N; base += 1024) {
        int i = base + threadIdx.x;
        int v = (i < N) ? deg[i] : 0;
        int x = v;
#pragma unroll
        for (int o = 1; o < 64; o <<= 1) {
            int y = __shfl_up(x, o, 64);
            if (lane >= o) x += y;
        }
        if (lane == 63) wsum[wid] = x;
        __syncthreads();
        if (wid == 0 && lane < 16) {
            int s = wsum[lane];
#pragma unroll
            for (int o = 1; o < 16; o <<= 1) {
                int y = __shfl_up(s, o, 16);
                if ((lane & 15) >= o) s += y;
            }
            wsum[lane] = s;
        }
        __syncthreads();
        int pre = (wid > 0) ? wsum[wid - 1] : 0;
        int incl = x + pre + carry_s;
        int excl = incl - v;
        if (i < N) { offs[i] = excl; cursor[i] = excl; }
        __syncthreads();
        if (threadIdx.x == 1023) carry_s = incl;
        __syncthreads();
    }
    if (threadIdx.x == 0) offs[N] = carry_s;
}

__global__ __launch_bounds__(256)
void fill_kernel(const int* __restrict__ ei, int* __restrict__ cursor,
                 int* __restrict__ csrc, int N, int E) {
    for (int e = blockIdx.x * blockDim.x + threadIdx.x; e < E;
         e += gridDim.x * blockDim.x) {
        int s = ei[e], d = ei[E + e];
        if ((unsigned)s >= (unsigned)N || (unsigned)d >= (unsigned)N) continue;
        int pos = atomicAdd(&cursor[d], 1);
        csrc[pos] = s;
    }
}

// ---------------- Layer 1 GEMM (x[N,128] @ W1[128,128]) + alpha dots ----------------
__global__ __launch_bounds__(128)
void gemm1_kernel(const void* __restrict__ x,
                  const void* __restrict__ W1,
                  const void* __restrict__ a_src,
                  const void* __restrict__ a_dst,
                  float* __restrict__ h1,
                  float* __restrict__ as1,
                  float* __restrict__ ad1,
                  int N, const int* __restrict__ dflag) {
    const bool bf = (*dflag != 0);
    __shared__ float xs[8][C1];
    const int t = threadIdx.x;
    const int n0 = blockIdx.x * 8;
#pragma unroll
    for (int j = 0; j < 8; ++j) {
        int n = n0 + j;
        xs[j][t] = (n < N) ? ldin(x, (size_t)n * C1 + t, bf) : 0.f;
    }
    __syncthreads();
    float acc[8] = {0.f,0.f,0.f,0.f,0.f,0.f,0.f,0.f};
    if (bf) {
        const __hip_bfloat16* W = (const __hip_bfloat16*)W1;
        for (int k = 0; k < 128; ++k) {
            float wv = (float)W[k * C1 + t];
#pragma unroll
            for (int j = 0; j < 8; ++j) acc[j] += xs[j][k] * wv;
        }
    } else {
        const float* W = (const float*)W1;
        for (int k = 0; k < 128; ++k) {
            float wv = W[k * C1 + t];
#pragma unroll
            for (int j = 0; j < 8; ++j) acc[j] += xs[j][k] * wv;
        }
    }
    const float asv = ldin(a_src, t, bf);
    const float adv = ldin(a_dst, t, bf);
    const int head = t >> 5;
#pragma unroll
    for (int j = 0; j < 8; ++j) {
        int n = n0 + j;
        if (n < N) h1[(size_t)n * C1 + t] = acc[j];
        float ps = acc[j] * asv;
        float pd = acc[j] * adv;
#pragma unroll
        for (int o = 16; o >= 1; o >>= 1) {
            ps += __shfl_xor(ps, o, 32);
            pd += __shfl_xor(pd, o, 32);
        }
        if ((t & 31) == 0 && n < N) {
            as1[n * 4 + head] = ps;
            ad1[n * 4 + head] = pd;
        }
    }
}

// ---------------- Layer 1 CSR gather: softmax-weighted sum + bias + ELU ----------------
__global__ __launch_bounds__(128)
void msg1_csr_kernel(const int* __restrict__ offs,
                     const int* __restrict__ csrc,
                     const float* __restrict__ h1,
                     const float* __restrict__ as1,
                     const float* __restrict__ ad1,
                     const void* __restrict__ b1,
                     float* __restrict__ out1,
                     int N, const int* __restrict__ dflag) {
    const bool bf = (*dflag != 0);
    const int d = blockIdx.x;
    if (d >= N) return;
    const int t = threadIdx.x;
    const int h = t >> 5;
    const int beg = offs[d], end = offs[d + 1];
    const float adh = ad1[d * 4 + h];
    float acc = 0.f, sumw = 0.f;
    int sNext = (beg < end) ? csrc[beg] : 0;
    for (int j = beg; j < end; ++j) {
        int s = sNext;
        sNext = (j + 1 < end) ? csrc[j + 1] : 0;
        float w = expf(lrelu(as1[s * 4 + h] + adh));
        sumw += w;
        acc += w * h1[(size_t)s * C1 + t];
    }
    float m = (sumw > 0.f) ? acc / sumw : 0.f;
    float v = m + ldin(b1, t, bf);
    out1[(size_t)d * C1 + t] = v > 0.f ? v : expm1f(v);
}

// ---------------- Layer 2 GEMM (h2[N,128] @ W2[128,64]) + alpha dots ----------------
__global__ __launch_bounds__(64)
void gemm2_kernel(const float* __restrict__ h2,
                  const void* __restrict__ W2,
                  const void* __restrict__ a_src,
                  const void* __restrict__ a_dst,
                  float* __restrict__ g2,
                  float* __restrict__ as2,
                  float* __restrict__ ad2,
                  int N, const int* __restrict__ dflag) {
    const bool bf = (*dflag != 0);
    __shared__ float xs[8][C1];
    const int t = threadIdx.x;
    const int n0 = blockIdx.x * 8;
#pragma unroll
    for (int j = 0; j < 8; ++j) {
        int n = n0 + j;
        if (n < N) {
            xs[j][t]      = h2[(size_t)n * C1 + t];
            xs[j][t + 64] = h2[(size_t)n * C1 + t + 64];
        } else {
            xs[j][t] = 0.f; xs[j][t + 64] = 0.f;
        }
    }
    __syncthreads();
    float acc[8] = {0.f,0.f,0.f,0.f,0.f,0.f,0.f,0.f};
    if (bf) {
        const __hip_bfloat16* W = (const __hip_bfloat16*)W2;
        for (int k = 0; k < 128; ++k) {
            float wv = (float)W[k * C2 + t];
#pragma unroll
            for (int j = 0; j < 8; ++j) acc[j] += xs[j][k] * wv;
        }
    } else {
        const float* W = (const float*)W2;
        for (int k = 0; k < 128; ++k) {
            float wv = W[k * C2 + t];
#pragma unroll
            for (int j = 0; j < 8; ++j) acc[j] += xs[j][k] * wv;
        }
    }
    const float asv = ldin(a_src, t, bf);
    const float adv = ldin(a_dst, t, bf);
#pragma unroll
    for (int j = 0; j < 8; ++j) {
        int n = n0 + j;
        if (n < N) g2[(size_t)n * C2 + t] = acc[j];
        float ps = acc[j] * asv;
        float pd = acc[j] * adv;
#pragma unroll
        for (int o = 32; o >= 1; o >>= 1) {
            ps += __shfl_xor(ps, o, 64);
            pd += __shfl_xor(pd, o, 64);
        }
        if (t == 0 && n < N) {
            as2[n] = ps;
            ad2[n] = pd;
        }
    }
}

// ---------------- Layer 2 CSR gather: softmax-weighted sum + bias + store ----------------
__global__ __launch_bounds__(256)
void msg2_csr_kernel(const int* __restrict__ offs,
                     const int* __restrict__ csrc,
                     const float* __restrict__ g2,
                     const float* __restrict__ as2,
                     const float* __restrict__ ad2,
                     const void* __restrict__ b2,
                     void* __restrict__ y,
                     int N, const int* __restrict__ dflag) {
    const bool bf = (*dflag != 0);
    const int wid = threadIdx.x >> 6;
    const int lane = threadIdx.x & 63;
    const int d = blockIdx.x * 4 + wid;
    if (d >= N) return;
    const int beg = offs[d], end = offs[d + 1];
    const float add = ad2[d];
    float acc = 0.f, sumw = 0.f;
    int sNext = (beg < end) ? csrc[beg] : 0;
    for (int j = beg; j < end; ++j) {
        int s = sNext;
        sNext = (j + 1 < end) ? csrc[j + 1] : 0;
        float w = expf(lrelu(as2[s] + add));
        sumw += w;
        acc += w * g2[(size_t)s * C2 + lane];
    }
    float m = (sumw > 0.f) ? acc / sumw : 0.f;
    float v = m + ldin(b2, lane, bf);
    if (bf) ((__hip_bfloat16*)y)[(size_t)d * C2 + lane] = __float2bfloat16(v);
    else    ((float*)y)[(size_t)d * C2 + lane] = v;
}

extern "C" void kernel_launch(void* const* d_in, const int* in_sizes, int n_in,
                              void* d_out, int out_size, void* d_ws, size_t ws_size,
                              hipStream_t stream) {
    const void* x    = d_in[0];
    const int*  ei   = (const int*)d_in[1];
    const void* W1   = d_in[2];
    const void* a_s1 = d_in[3];
    const void* a_d1 = d_in[4];
    const void* b1   = d_in[5];
    const void* W2   = d_in[6];
    const void* a_s2 = d_in[7];
    const void* a_d2 = d_in[8];
    const void* b2   = d_in[9];

    const int N = in_sizes[0] / C1;
    const int E = in_sizes[1] / 2;

    auto align16 = [](size_t v) { return (v + 15) & ~(size_t)15; };
    const size_t RF   = 16;                                  // dtype flag
    const size_t ROFF = align16((size_t)(N + 1) * 4);        // offs
    const size_t RCUR = align16((size_t)N * 4);              // deg/cursor
    const size_t RSRC = align16((size_t)E * 4);              // csr src ids
    const size_t R1   = align16((size_t)N * C1 * 4);         // h1 / g2
    const size_t R2   = align16((size_t)N * 8 * 4);          // as1+ad1 (reused as2/ad2)
    const size_t R4   = align16((size_t)N * C1 * 4);         // out1

    char* base = (char*)d_ws;
    int*  dflag = (int*)base;
    int*  offs   = (int*)(base + RF);
    int*  cursor = (int*)(base + RF + ROFF);
    int*  csrc   = (int*)(base + RF + ROFF + RCUR);
    char* R1p = base + RF + ROFF + RCUR + RSRC;
    char* R2p = R1p + R1;
    char* R4p = R2p + R2;
    (void)ws_size; (void)R4;

    float* h1  = (float*)R1p;
    float* g2  = (float*)R1p;                  // h1 dead after msg1
    float* as1 = (float*)R2p;                  // N*4
    float* ad1 = as1 + (size_t)N * 4;          // N*4
    float* as2 = (float*)R2p;                  // N (as1/ad1 dead by then)
    float* ad2 = as2 + N;                      // N
    float* out1 = (float*)R4p;                 // N*C1

    const int nb_nodes = (N + 7) / 8;

    detect_kernel<<<1, 256, 0, stream>>>((const unsigned*)x, 2048, dflag);
    hipMemsetAsync(cursor, 0, (size_t)N * 4, stream);
    count_kernel<<<1024, 256, 0, stream>>>(ei, cursor, N, E);
    scan_kernel<<<1, 1024, 0, stream>>>(cursor, offs, cursor, N);
    fill_kernel<<<1024, 256, 0, stream>>>(ei, cursor, csrc, N, E);

    gemm1_kernel<<<nb_nodes, 128, 0, stream>>>(x, W1, a_s1, a_d1, h1, as1, ad1, N, dflag);
    msg1_csr_kernel<<<N, 128, 0, stream>>>(offs, csrc, h1, as1, ad1, b1, out1, N, dflag);
    gemm2_kernel<<<nb_nodes, 64, 0, stream>>>(out1, W2, a_s2, a_d2, g2, as2, ad2, N, dflag);
    msg2_csr_kernel<<<(N + 3) / 4, 256, 0, stream>>>(offs, csrc, g2, as2, ad2, b2, d_out, N, dflag);
}

// Round 5
// 461.625 us; speedup vs baseline: 2.2341x; 1.0909x over previous
//
#include <hip/hip_runtime.h>
#include <hip/hip_bf16.h>

#define C1 128   // heads1(4) * hid(32)
#define C2 64    // out channels layer 2

typedef __attribute__((ext_vector_type(8))) short short8;
typedef __attribute__((ext_vector_type(4))) float floatx4;

__device__ __forceinline__ float lrelu(float v) { return v > 0.f ? v : 0.2f * v; }

__device__ __forceinline__ float ldin(const void* p, size_t i, bool bf) {
    return bf ? (float)((const __hip_bfloat16*)p)[i] : ((const float*)p)[i];
}
__device__ __forceinline__ float ldh(const float* p, size_t i) { return p[i]; }
__device__ __forceinline__ float ldh(const __hip_bfloat16* p, size_t i) { return (float)p[i]; }

// ---------------- dtype detection (bf16 vs fp32 inputs) ----------------
__global__ __launch_bounds__(256)
void detect_kernel(const unsigned* __restrict__ xw, int nwords, int* __restrict__ flag) {
    __shared__ int cnt;
    if (threadIdx.x == 0) cnt = 0;
    __syncthreads();
    int my = 0;
    for (int i = threadIdx.x; i < nwords; i += 256) {
        unsigned lo = xw[i] & 0xFFFFu;
        int e = (lo >> 7) & 0xFF;
        if (e >= 110 && e <= 140) ++my;
    }
    atomicAdd(&cnt, my);
    __syncthreads();
    if (threadIdx.x == 0) *flag = (cnt * 2 > nwords) ? 1 : 0;
}

// ---------------- CSR build ----------------
__global__ __launch_bounds__(256)
void count_kernel(const int* __restrict__ ei, int* __restrict__ deg, int N, int E) {
    for (int e = blockIdx.x * blockDim.x + threadIdx.x; e < E;
         e += gridDim.x * blockDim.x) {
        int d = ei[E + e];
        if ((unsigned)d < (unsigned)N) atomicAdd(&deg[d], 1);
    }
}

// phase A: per-1024-chunk exclusive scan + block totals
__global__ __launch_bounds__(1024)
void scanA_kernel(const int* __restrict__ deg, int* __restrict__ offs,
                  int* __restrict__ bsum, int N) {
    __shared__ int wsum[16];
    const int i = blockIdx.x * 1024 + threadIdx.x;
    const int lane = threadIdx.x & 63, wid = threadIdx.x >> 6;
    int v = (i < N) ? deg[i] : 0;
    int x = v;
#pragma unroll
    for (int o = 1; o < 64; o <<= 1) {
        int y = __shfl_up(x, o, 64);
        if (lane >= o) x += y;
    }
    if (lane == 63) wsum[wid] = x;
    __syncthreads();
    if (wid == 0 && lane < 16) {
        int s = wsum[lane];
#pragma unroll
        for (int o = 1; o < 16; o <<= 1) {
            int y = __shfl_up(s, o, 16);
            if (lane >= o) s += y;
        }
        wsum[lane] = s;
    }
    __syncthreads();
    int pre = (wid > 0) ? wsum[wid - 1] : 0;
    int incl = x + pre;
    if (i < N) offs[i] = incl - v;
    if (threadIdx.x == 1023) bsum[blockIdx.x] = incl;
}

// phase B: scan block totals (nb <= 64 fast path), write offs[N]=total
__global__ __launch_bounds__(64)
void scanB_kernel(int* __restrict__ bsum, int* __restrict__ offs_end, int nb) {
    const int lane = threadIdx.x;
    if (nb <= 64) {
        int v = (lane < nb) ? bsum[lane] : 0;
        int x = v;
#pragma unroll
        for (int o = 1; o < 64; o <<= 1) {
            int y = __shfl_up(x, o, 64);
            if (lane >= o) x += y;
        }
        if (lane < nb) bsum[lane] = x - v;
        int tot = __shfl(x, 63, 64);
        if (lane == 0) *offs_end = tot;
    } else if (lane == 0) {
        int run = 0;
        for (int b = 0; b < nb; ++b) { int t = bsum[b]; bsum[b] = run; run += t; }
        *offs_end = run;
    }
}

// phase C: add block prefix, copy to cursor
__global__ __launch_bounds__(1024)
void scanC_kernel(int* __restrict__ offs, int* __restrict__ cursor,
                  const int* __restrict__ bsum, int N) {
    const int i = blockIdx.x * 1024 + threadIdx.x;
    if (i < N) {
        int o = offs[i] + bsum[blockIdx.x];
        offs[i] = o;
        cursor[i] = o;
    }
}

__global__ __launch_bounds__(256)
void fill_kernel(const int* __restrict__ ei, int* __restrict__ cursor,
                 int* __restrict__ csrc, int N, int E) {
    for (int e = blockIdx.x * blockDim.x + threadIdx.x; e < E;
         e += gridDim.x * blockDim.x) {
        int s = ei[e], d = ei[E + e];
        if ((unsigned)s >= (unsigned)N || (unsigned)d >= (unsigned)N) continue;
        int pos = atomicAdd(&cursor[d], 1);
        csrc[pos] = s;
    }
}

// ---------------- Layer 1 GEMM via MFMA (bf16 mode only) ----------------
// x[N,128]bf16 @ W1[128,128]bf16 -> h1 bf16, + fused alpha dots (fp32).
__global__ __launch_bounds__(256)
void gemm1_mfma_kernel(const void* __restrict__ xv, const void* __restrict__ W1v,
                       const void* __restrict__ a_srcv, const void* __restrict__ a_dstv,
                       __hip_bfloat16* __restrict__ h1b,
                       float* __restrict__ as1, float* __restrict__ ad1,
                       int N, const int* __restrict__ dflag) {
    if (*dflag == 0) return;   // fp32 inputs -> vector fallback kernel handles it
    // W1 transposed into LDS: Bs[col][k], stride 136 (pad 8) -> 2-way banks (free)
    __shared__ __align__(16) unsigned short Bs[128 * 136];
    const unsigned short* Wg = (const unsigned short*)W1v;
    for (int i = threadIdx.x; i < 128 * 64; i += 256) {
        int col = i & 127;
        int k = (i >> 7) * 2;
        unsigned w0 = Wg[k * 128 + col];
        unsigned w1 = Wg[(k + 1) * 128 + col];
        *(unsigned*)&Bs[col * 136 + k] = w0 | (w1 << 16);
    }
    __syncthreads();

    const int lane = threadIdx.x & 63, ww = threadIdx.x >> 6;
    const int quad = lane >> 4, l16 = lane & 15;
    const int nodeBase = blockIdx.x * 64 + ww * 16;
    int arow = nodeBase + l16;
    if (arow >= N) arow = N - 1;                       // clamp loads; stores guarded
    const short* xp = (const short*)xv + (size_t)arow * C1 + quad * 8;
    short8 afr[4];
#pragma unroll
    for (int kk = 0; kk < 4; ++kk) afr[kk] = *(const short8*)(xp + kk * 32);

    const __hip_bfloat16* asrc = (const __hip_bfloat16*)a_srcv;
    const __hip_bfloat16* adst = (const __hip_bfloat16*)a_dstv;
    float sacc[4], dacc[4];
#pragma unroll
    for (int ct = 0; ct < 8; ++ct) {
        floatx4 acc = {0.f, 0.f, 0.f, 0.f};
        const int col = ct * 16 + l16;
        const unsigned short* bbase = &Bs[col * 136 + quad * 8];
#pragma unroll
        for (int kk = 0; kk < 4; ++kk) {
            short8 bfr = *(const short8*)(bbase + kk * 32);
            acc = __builtin_amdgcn_mfma_f32_16x16x32_bf16(afr[kk], bfr, acc, 0, 0, 0);
        }
        // C/D layout: col=lane&15, row=quad*4+reg  [m89/m91 verified]
#pragma unroll
        for (int reg = 0; reg < 4; ++reg) {
            int node = nodeBase + quad * 4 + reg;
            if (node < N) h1b[(size_t)node * C1 + col] = __float2bfloat16(acc[reg]);
        }
        float av = (float)asrc[col];
        float dv = (float)adst[col];
        if ((ct & 1) == 0) {
#pragma unroll
            for (int r = 0; r < 4; ++r) { sacc[r] = 0.f; dacc[r] = 0.f; }
        }
#pragma unroll
        for (int reg = 0; reg < 4; ++reg) {
            float ts = acc[reg] * av;
            float td = acc[reg] * dv;
#pragma unroll
            for (int o = 1; o < 16; o <<= 1) {
                ts += __shfl_xor(ts, o, 64);
                td += __shfl_xor(td, o, 64);
            }
            sacc[reg] += ts;
            dacc[reg] += td;
        }
        if ((ct & 1) == 1) {
            int h = ct >> 1;
            if (l16 == 0) {
#pragma unroll
                for (int reg = 0; reg < 4; ++reg) {
                    int node = nodeBase + quad * 4 + reg;
                    if (node < N) {
                        as1[node * 4 + h] = sacc[reg];
                        ad1[node * 4 + h] = dacc[reg];
                    }
                }
            }
        }
    }
}

// ---------------- Layer 1 GEMM vector fallback (fp32 inputs only) ----------------
__global__ __launch_bounds__(128)
void gemm1_vec_kernel(const float* __restrict__ x, const float* __restrict__ W1,
                      const float* __restrict__ a_src, const float* __restrict__ a_dst,
                      float* __restrict__ h1, float* __restrict__ as1,
                      float* __restrict__ ad1, int N, const int* __restrict__ dflag) {
    if (*dflag != 0) return;
    __shared__ float xs[8][C1];
    const int t = threadIdx.x;
    const int n0 = blockIdx.x * 8;
#pragma unroll
    for (int j = 0; j < 8; ++j) {
        int n = n0 + j;
        xs[j][t] = (n < N) ? x[(size_t)n * C1 + t] : 0.f;
    }
    __syncthreads();
    float acc[8] = {0.f,0.f,0.f,0.f,0.f,0.f,0.f,0.f};
    for (int k = 0; k < 128; ++k) {
        float wv = W1[k * C1 + t];
#pragma unroll
        for (int j = 0; j < 8; ++j) acc[j] += xs[j][k] * wv;
    }
    const float asv = a_src[t];
    const float adv = a_dst[t];
    const int head = t >> 5;
#pragma unroll
    for (int j = 0; j < 8; ++j) {
        int n = n0 + j;
        if (n < N) h1[(size_t)n * C1 + t] = acc[j];
        float ps = acc[j] * asv;
        float pd = acc[j] * adv;
#pragma unroll
        for (int o = 16; o >= 1; o >>= 1) {
            ps += __shfl_xor(ps, o, 32);
            pd += __shfl_xor(pd, o, 32);
        }
        if ((t & 31) == 0 && n < N) {
            as1[n * 4 + head] = ps;
            ad1[n * 4 + head] = pd;
        }
    }
}

// ---------------- Layer 1 CSR gather ----------------
template <typename HT>
__device__ __forceinline__ void msg1_body(const int* __restrict__ offs,
                                          const int* __restrict__ csrc,
                                          const HT* __restrict__ h1,
                                          const float* __restrict__ as1,
                                          const float* __restrict__ ad1,
                                          const void* __restrict__ b1,
                                          float* __restrict__ out1,
                                          int d, bool bf) {
    const int t = threadIdx.x;
    const int h = t >> 5;
    const int beg = offs[d], end = offs[d + 1];
    const float adh = ad1[d * 4 + h];
    float acc = 0.f, sumw = 0.f;
    int sNext = (beg < end) ? csrc[beg] : 0;
    for (int j = beg; j < end; ++j) {
        int s = sNext;
        sNext = (j + 1 < end) ? csrc[j + 1] : 0;
        float w = __expf(lrelu(as1[s * 4 + h] + adh));
        sumw += w;
        acc += w * ldh(h1, (size_t)s * C1 + t);
    }
    float m = (sumw > 0.f) ? acc / sumw : 0.f;
    float v = m + ldin(b1, t, bf);
    out1[(size_t)d * C1 + t] = v > 0.f ? v : expm1f(v);
}

__global__ __launch_bounds__(128)
void msg1_csr_kernel(const int* __restrict__ offs, const int* __restrict__ csrc,
                     const void* __restrict__ h1, const float* __restrict__ as1,
                     const float* __restrict__ ad1, const void* __restrict__ b1,
                     float* __restrict__ out1, int N, const int* __restrict__ dflag) {
    const bool bf = (*dflag != 0);
    const int d = blockIdx.x;
    if (d >= N) return;
    if (bf) msg1_body((const int*)offs, csrc, (const __hip_bfloat16*)h1, as1, ad1, b1, out1, d, true);
    else    msg1_body((const int*)offs, csrc, (const float*)h1,          as1, ad1, b1, out1, d, false);
}

// ---------------- Layer 2 GEMM (h2[N,128]fp32 @ W2[128,64]) + alpha dots ----------------
__global__ __launch_bounds__(64)
void gemm2_kernel(const float* __restrict__ h2, const void* __restrict__ W2,
                  const void* __restrict__ a_src, const void* __restrict__ a_dst,
                  void* __restrict__ g2, float* __restrict__ as2,
                  float* __restrict__ ad2, int N, const int* __restrict__ dflag) {
    const bool bf = (*dflag != 0);
    __shared__ __align__(16) float xs[8][C1];
    const int t = threadIdx.x;
    const int n0 = blockIdx.x * 8;
#pragma unroll
    for (int j = 0; j < 8; ++j) {
        int n = n0 + j;
        if (n < N) {
            float2 v = *(const float2*)&h2[(size_t)n * C1 + t * 2];
            xs[j][t * 2] = v.x;
            xs[j][t * 2 + 1] = v.y;
        } else {
            xs[j][t * 2] = 0.f;
            xs[j][t * 2 + 1] = 0.f;
        }
    }
    __syncthreads();
    float acc[8] = {0.f,0.f,0.f,0.f,0.f,0.f,0.f,0.f};
    const __hip_bfloat16* Wb = (const __hip_bfloat16*)W2;
    const float* Wf = (const float*)W2;
    for (int k = 0; k < 128; k += 4) {
        float w0, w1, w2, w3;
        if (bf) {
            w0 = (float)Wb[(k + 0) * C2 + t]; w1 = (float)Wb[(k + 1) * C2 + t];
            w2 = (float)Wb[(k + 2) * C2 + t]; w3 = (float)Wb[(k + 3) * C2 + t];
        } else {
            w0 = Wf[(k + 0) * C2 + t]; w1 = Wf[(k + 1) * C2 + t];
            w2 = Wf[(k + 2) * C2 + t]; w3 = Wf[(k + 3) * C2 + t];
        }
#pragma unroll
        for (int j = 0; j < 8; ++j) {
            float4 xv = *(const float4*)&xs[j][k];
            acc[j] += xv.x * w0 + xv.y * w1 + xv.z * w2 + xv.w * w3;
        }
    }
    const float asv = ldin(a_src, t, bf);
    const float adv = ldin(a_dst, t, bf);
#pragma unroll
    for (int j = 0; j < 8; ++j) {
        int n = n0 + j;
        if (n < N) {
            if (bf) ((__hip_bfloat16*)g2)[(size_t)n * C2 + t] = __float2bfloat16(acc[j]);
            else    ((float*)g2)[(size_t)n * C2 + t] = acc[j];
        }
        float ps = acc[j] * asv;
        float pd = acc[j] * adv;
#pragma unroll
        for (int o = 32; o >= 1; o >>= 1) {
            ps += __shfl_xor(ps, o, 64);
            pd += __shfl_xor(pd, o, 64);
        }
        if (t == 0 && n < N) { as2[n] = ps; ad2[n] = pd; }
    }
}

// ---------------- Layer 2 CSR gather + bias + store ----------------
template <typename HT>
__device__ __forceinline__ void msg2_body(const int* __restrict__ offs,
                                          const int* __restrict__ csrc,
                                          const HT* __restrict__ g2,
                                          const float* __restrict__ as2,
                                          const float* __restrict__ ad2,
                                          const void* __restrict__ b2,
                                          void* __restrict__ y, int d, bool bf) {
    const int lane = threadIdx.x & 63;
    const int beg = offs[d], end = offs[d + 1];
    const float add = ad2[d];
    float acc = 0.f, sumw = 0.f;
    int sNext = (beg < end) ? csrc[beg] : 0;
    for (int j = beg; j < end; ++j) {
        int s = sNext;
        sNext = (j + 1 < end) ? csrc[j + 1] : 0;
        float w = __expf(lrelu(as2[s] + add));
        sumw += w;
        acc += w * ldh(g2, (size_t)s * C2 + lane);
    }
    float m = (sumw > 0.f) ? acc / sumw : 0.f;
    float v = m + ldin(b2, lane, bf);
    if (bf) ((__hip_bfloat16*)y)[(size_t)d * C2 + lane] = __float2bfloat16(v);
    else    ((float*)y)[(size_t)d * C2 + lane] = v;
}

__global__ __launch_bounds__(256)
void msg2_csr_kernel(const int* __restrict__ offs, const int* __restrict__ csrc,
                     const void* __restrict__ g2, const float* __restrict__ as2,
                     const float* __restrict__ ad2, const void* __restrict__ b2,
                     void* __restrict__ y, int N, const int* __restrict__ dflag) {
    const bool bf = (*dflag != 0);
    const int d = blockIdx.x * 4 + (threadIdx.x >> 6);
    if (d >= N) return;
    if (bf) msg2_body(offs, csrc, (const __hip_bfloat16*)g2, as2, ad2, b2, y, d, true);
    else    msg2_body(offs, csrc, (const float*)g2,          as2, ad2, b2, y, d, false);
}

extern "C" void kernel_launch(void* const* d_in, const int* in_sizes, int n_in,
                              void* d_out, int out_size, void* d_ws, size_t ws_size,
                              hipStream_t stream) {
    const void* x    = d_in[0];
    const int*  ei   = (const int*)d_in[1];
    const void* W1   = d_in[2];
    const void* a_s1 = d_in[3];
    const void* a_d1 = d_in[4];
    const void* b1   = d_in[5];
    const void* W2   = d_in[6];
    const void* a_s2 = d_in[7];
    const void* a_d2 = d_in[8];
    const void* b2   = d_in[9];

    const int N = in_sizes[0] / C1;
    const int E = in_sizes[1] / 2;

    auto align16 = [](size_t v) { return (v + 15) & ~(size_t)15; };
    const size_t RF   = 16;
    const size_t ROFF = align16((size_t)(N + 1) * 4);
    const size_t RCUR = align16((size_t)N * 4);
    const size_t RBS  = 256;                                 // block sums (<=64 ints)
    const size_t RSRC = align16((size_t)E * 4);
    const size_t R1   = align16((size_t)N * C1 * 4);         // h1(fp32 worst) / g2
    const size_t R2   = align16((size_t)N * 8 * 4);          // as1+ad1 / as2+ad2
    // R4: out1 fp32

    char* base = (char*)d_ws;
    int*  dflag  = (int*)base;
    int*  offs   = (int*)(base + RF);
    int*  cursor = (int*)(base + RF + ROFF);
    int*  bsum   = (int*)(base + RF + ROFF + RCUR);
    int*  csrc   = (int*)(base + RF + ROFF + RCUR + RBS);
    char* R1p = base + RF + ROFF + RCUR + RBS + RSRC;
    char* R2p = R1p + R1;
    char* R4p = R2p + R2;
    (void)ws_size;

    void*  h1  = (void*)R1p;                   // bf16 (bf mode) or fp32 (fallback)
    void*  g2  = (void*)R1p;                   // h1 dead after msg1
    float* as1 = (float*)R2p;
    float* ad1 = as1 + (size_t)N * 4;
    float* as2 = (float*)R2p;
    float* ad2 = as2 + N;
    float* out1 = (float*)R4p;

    const int nbScan = (N + 1023) / 1024;

    detect_kernel<<<1, 256, 0, stream>>>((const unsigned*)x, 2048, dflag);
    hipMemsetAsync(cursor, 0, (size_t)N * 4, stream);
    count_kernel<<<1024, 256, 0, stream>>>(ei, cursor, N, E);
    scanA_kernel<<<nbScan, 1024, 0, stream>>>(cursor, offs, bsum, N);
    scanB_kernel<<<1, 64, 0, stream>>>(bsum, &offs[N], nbScan);
    scanC_kernel<<<nbScan, 1024, 0, stream>>>(offs, cursor, bsum, N);
    fill_kernel<<<1024, 256, 0, stream>>>(ei, cursor, csrc, N, E);

    gemm1_mfma_kernel<<<(N + 63) / 64, 256, 0, stream>>>(x, W1, a_s1, a_d1,
        (__hip_bfloat16*)h1, as1, ad1, N, dflag);
    gemm1_vec_kernel<<<(N + 7) / 8, 128, 0, stream>>>((const float*)x, (const float*)W1,
        (const float*)a_s1, (const float*)a_d1, (float*)h1, as1, ad1, N, dflag);

    msg1_csr_kernel<<<N, 128, 0, stream>>>(offs, csrc, h1, as1, ad1, b1, out1, N, dflag);
    gemm2_kernel<<<(N + 7) / 8, 64, 0, stream>>>(out1, W2, a_s2, a_d2, g2, as2, ad2, N, dflag);
    msg2_csr_kernel<<<(N + 3) / 4, 256, 0, stream>>>(offs, csrc, g2, as2, ad2, b2, d_out, N, dflag);
}

// Round 6
// 388.316 us; speedup vs baseline: 2.6559x; 1.1888x over previous
//
#include <hip/hip_runtime.h>
#include <hip/hip_bf16.h>

#define C1 128   // heads1(4) * hid(32)
#define C2 64    // out channels layer 2

typedef __attribute__((ext_vector_type(8))) short short8;
typedef __attribute__((ext_vector_type(4))) float floatx4;

__device__ __forceinline__ float lrelu(float v) { return v > 0.f ? v : 0.2f * v; }

__device__ __forceinline__ float ldin(const void* p, size_t i, bool bf) {
    return bf ? (float)((const __hip_bfloat16*)p)[i] : ((const float*)p)[i];
}
__device__ __forceinline__ float ldh(const float* p, size_t i) { return p[i]; }
__device__ __forceinline__ float ldh(const __hip_bfloat16* p, size_t i) { return (float)p[i]; }
__device__ __forceinline__ void stout(float* p, size_t i, float v) { p[i] = v; }
__device__ __forceinline__ void stout(__hip_bfloat16* p, size_t i, float v) { p[i] = __float2bfloat16(v); }

// ---------------- dtype detection (bf16 vs fp32 inputs) ----------------
__global__ __launch_bounds__(256)
void detect_kernel(const unsigned* __restrict__ xw, int nwords, int* __restrict__ flag) {
    __shared__ int cnt;
    if (threadIdx.x == 0) cnt = 0;
    __syncthreads();
    int my = 0;
    for (int i = threadIdx.x; i < nwords; i += 256) {
        unsigned lo = xw[i] & 0xFFFFu;
        int e = (lo >> 7) & 0xFF;
        if (e >= 110 && e <= 140) ++my;
    }
    atomicAdd(&cnt, my);
    __syncthreads();
    if (threadIdx.x == 0) *flag = (cnt * 2 > nwords) ? 1 : 0;
}

// ---------------- CSR build ----------------
__global__ __launch_bounds__(256)
void count_kernel(const int* __restrict__ ei, int* __restrict__ deg, int N, int E) {
    for (int e = blockIdx.x * blockDim.x + threadIdx.x; e < E;
         e += gridDim.x * blockDim.x) {
        int d = ei[E + e];
        if ((unsigned)d < (unsigned)N) atomicAdd(&deg[d], 1);
    }
}

__global__ __launch_bounds__(1024)
void scanA_kernel(const int* __restrict__ deg, int* __restrict__ offs,
                  int* __restrict__ bsum, int N) {
    __shared__ int wsum[16];
    const int i = blockIdx.x * 1024 + threadIdx.x;
    const int lane = threadIdx.x & 63, wid = threadIdx.x >> 6;
    int v = (i < N) ? deg[i] : 0;
    int x = v;
#pragma unroll
    for (int o = 1; o < 64; o <<= 1) {
        int y = __shfl_up(x, o, 64);
        if (lane >= o) x += y;
    }
    if (lane == 63) wsum[wid] = x;
    __syncthreads();
    if (wid == 0 && lane < 16) {
        int s = wsum[lane];
#pragma unroll
        for (int o = 1; o < 16; o <<= 1) {
            int y = __shfl_up(s, o, 16);
            if (lane >= o) s += y;
        }
        wsum[lane] = s;
    }
    __syncthreads();
    int pre = (wid > 0) ? wsum[wid - 1] : 0;
    int incl = x + pre;
    if (i < N) offs[i] = incl - v;
    if (threadIdx.x == 1023) bsum[blockIdx.x] = incl;
}

__global__ __launch_bounds__(64)
void scanB_kernel(int* __restrict__ bsum, int* __restrict__ offs_end, int nb) {
    const int lane = threadIdx.x;
    if (nb <= 64) {
        int v = (lane < nb) ? bsum[lane] : 0;
        int x = v;
#pragma unroll
        for (int o = 1; o < 64; o <<= 1) {
            int y = __shfl_up(x, o, 64);
            if (lane >= o) x += y;
        }
        if (lane < nb) bsum[lane] = x - v;
        int tot = __shfl(x, 63, 64);
        if (lane == 0) *offs_end = tot;
    } else if (lane == 0) {
        int run = 0;
        for (int b = 0; b < nb; ++b) { int t = bsum[b]; bsum[b] = run; run += t; }
        *offs_end = run;
    }
}

__global__ __launch_bounds__(1024)
void scanC_kernel(int* __restrict__ offs, int* __restrict__ cursor,
                  const int* __restrict__ bsum, int N) {
    const int i = blockIdx.x * 1024 + threadIdx.x;
    if (i < N) {
        int o = offs[i] + bsum[blockIdx.x];
        offs[i] = o;
        cursor[i] = o;
    }
}

__global__ __launch_bounds__(256)
void fill_kernel(const int* __restrict__ ei, int* __restrict__ cursor,
                 int* __restrict__ csrc, int N, int E) {
    for (int e = blockIdx.x * blockDim.x + threadIdx.x; e < E;
         e += gridDim.x * blockDim.x) {
        int s = ei[e], d = ei[E + e];
        if ((unsigned)s >= (unsigned)N || (unsigned)d >= (unsigned)N) continue;
        int pos = atomicAdd(&cursor[d], 1);
        csrc[pos] = s;
    }
}

// ---------------- Layer 1 GEMM via MFMA (bf16 mode) ----------------
__global__ __launch_bounds__(256)
void gemm1_mfma_kernel(const void* __restrict__ xv, const void* __restrict__ W1v,
                       const void* __restrict__ a_srcv, const void* __restrict__ a_dstv,
                       __hip_bfloat16* __restrict__ h1b,
                       float* __restrict__ as1, float* __restrict__ ad1,
                       int N, const int* __restrict__ dflag) {
    if (*dflag == 0) return;
    __shared__ __align__(16) unsigned short Bs[128 * 136];
    const unsigned short* Wg = (const unsigned short*)W1v;
    for (int i = threadIdx.x; i < 128 * 64; i += 256) {
        int col = i & 127;
        int k = (i >> 7) * 2;
        unsigned w0 = Wg[k * 128 + col];
        unsigned w1 = Wg[(k + 1) * 128 + col];
        *(unsigned*)&Bs[col * 136 + k] = w0 | (w1 << 16);
    }
    __syncthreads();

    const int lane = threadIdx.x & 63, ww = threadIdx.x >> 6;
    const int quad = lane >> 4, l16 = lane & 15;
    const int nodeBase = blockIdx.x * 64 + ww * 16;
    int arow = nodeBase + l16;
    if (arow >= N) arow = N - 1;
    const short* xp = (const short*)xv + (size_t)arow * C1 + quad * 8;
    short8 afr[4];
#pragma unroll
    for (int kk = 0; kk < 4; ++kk) afr[kk] = *(const short8*)(xp + kk * 32);

    const __hip_bfloat16* asrc = (const __hip_bfloat16*)a_srcv;
    const __hip_bfloat16* adst = (const __hip_bfloat16*)a_dstv;
    float sacc[4], dacc[4];
#pragma unroll
    for (int ct = 0; ct < 8; ++ct) {
        floatx4 acc = {0.f, 0.f, 0.f, 0.f};
        const int col = ct * 16 + l16;
        const unsigned short* bbase = &Bs[col * 136 + quad * 8];
#pragma unroll
        for (int kk = 0; kk < 4; ++kk) {
            short8 bfr = *(const short8*)(bbase + kk * 32);
            acc = __builtin_amdgcn_mfma_f32_16x16x32_bf16(afr[kk], bfr, acc, 0, 0, 0);
        }
#pragma unroll
        for (int reg = 0; reg < 4; ++reg) {
            int node = nodeBase + quad * 4 + reg;
            if (node < N) h1b[(size_t)node * C1 + col] = __float2bfloat16(acc[reg]);
        }
        float av = (float)asrc[col];
        float dv = (float)adst[col];
        if ((ct & 1) == 0) {
#pragma unroll
            for (int r = 0; r < 4; ++r) { sacc[r] = 0.f; dacc[r] = 0.f; }
        }
#pragma unroll
        for (int reg = 0; reg < 4; ++reg) {
            float ts = acc[reg] * av;
            float td = acc[reg] * dv;
#pragma unroll
            for (int o = 1; o < 16; o <<= 1) {
                ts += __shfl_xor(ts, o, 64);
                td += __shfl_xor(td, o, 64);
            }
            sacc[reg] += ts;
            dacc[reg] += td;
        }
        if ((ct & 1) == 1 && l16 == 0) {
            int h = ct >> 1;
#pragma unroll
            for (int reg = 0; reg < 4; ++reg) {
                int node = nodeBase + quad * 4 + reg;
                if (node < N) {
                    as1[node * 4 + h] = sacc[reg];
                    ad1[node * 4 + h] = dacc[reg];
                }
            }
        }
    }
}

// ---------------- Layer 1 GEMM vector fallback (fp32 inputs) ----------------
__global__ __launch_bounds__(128)
void gemm1_vec_kernel(const float* __restrict__ x, const float* __restrict__ W1,
                      const float* __restrict__ a_src, const float* __restrict__ a_dst,
                      float* __restrict__ h1, float* __restrict__ as1,
                      float* __restrict__ ad1, int N, const int* __restrict__ dflag) {
    if (*dflag != 0) return;
    __shared__ float xs[8][C1];
    const int t = threadIdx.x;
    const int n0 = blockIdx.x * 8;
#pragma unroll
    for (int j = 0; j < 8; ++j) {
        int n = n0 + j;
        xs[j][t] = (n < N) ? x[(size_t)n * C1 + t] : 0.f;
    }
    __syncthreads();
    float acc[8] = {0.f,0.f,0.f,0.f,0.f,0.f,0.f,0.f};
    for (int k = 0; k < 128; ++k) {
        float wv = W1[k * C1 + t];
#pragma unroll
        for (int j = 0; j < 8; ++j) acc[j] += xs[j][k] * wv;
    }
    const float asv = a_src[t];
    const float adv = a_dst[t];
    const int head = t >> 5;
#pragma unroll
    for (int j = 0; j < 8; ++j) {
        int n = n0 + j;
        if (n < N) h1[(size_t)n * C1 + t] = acc[j];
        float ps = acc[j] * asv;
        float pd = acc[j] * adv;
#pragma unroll
        for (int o = 16; o >= 1; o >>= 1) {
            ps += __shfl_xor(ps, o, 32);
            pd += __shfl_xor(pd, o, 32);
        }
        if ((t & 31) == 0 && n < N) {
            as1[n * 4 + head] = ps;
            ad1[n * 4 + head] = pd;
        }
    }
}

// ---------------- Layer 1 CSR gather (4-deep MLP strip-mine) ----------------
template <typename HT, typename OT>
__device__ __forceinline__ void msg1_body(const int* __restrict__ offs,
                                          const int* __restrict__ csrc,
                                          const HT* __restrict__ h1,
                                          const float* __restrict__ as1,
                                          const float* __restrict__ ad1,
                                          const void* __restrict__ b1,
                                          OT* __restrict__ out1,
                                          int d, bool bf) {
    const int t = threadIdx.x;
    const int h = t >> 5;
    const int beg = offs[d], end = offs[d + 1];
    const float adh = ad1[d * 4 + h];
    float acc = 0.f, sumw = 0.f;
    for (int jj = beg; jj < end; jj += 4) {
        int i1 = jj + 1 < end ? jj + 1 : end - 1;
        int i2 = jj + 2 < end ? jj + 2 : end - 1;
        int i3 = jj + 3 < end ? jj + 3 : end - 1;
        int s0 = csrc[jj], s1 = csrc[i1], s2 = csrc[i2], s3 = csrc[i3];
        float a0 = as1[s0 * 4 + h], a1 = as1[s1 * 4 + h];
        float a2 = as1[s2 * 4 + h], a3 = as1[s3 * 4 + h];
        float v0 = ldh(h1, (size_t)s0 * C1 + t), v1 = ldh(h1, (size_t)s1 * C1 + t);
        float v2 = ldh(h1, (size_t)s2 * C1 + t), v3 = ldh(h1, (size_t)s3 * C1 + t);
        float w0 = __expf(lrelu(a0 + adh));
        float w1 = (jj + 1 < end) ? __expf(lrelu(a1 + adh)) : 0.f;
        float w2 = (jj + 2 < end) ? __expf(lrelu(a2 + adh)) : 0.f;
        float w3 = (jj + 3 < end) ? __expf(lrelu(a3 + adh)) : 0.f;
        sumw += (w0 + w1) + (w2 + w3);
        acc += w0 * v0 + w1 * v1 + w2 * v2 + w3 * v3;
    }
    float m = (sumw > 0.f) ? acc / sumw : 0.f;
    float v = m + ldin(b1, t, bf);
    stout(out1, (size_t)d * C1 + t, v > 0.f ? v : expm1f(v));
}

__global__ __launch_bounds__(128)
void msg1_csr_kernel(const int* __restrict__ offs, const int* __restrict__ csrc,
                     const void* __restrict__ h1, const float* __restrict__ as1,
                     const float* __restrict__ ad1, const void* __restrict__ b1,
                     void* __restrict__ out1, int N, const int* __restrict__ dflag) {
    const bool bf = (*dflag != 0);
    const int d = blockIdx.x;
    if (d >= N) return;
    if (bf) msg1_body(offs, csrc, (const __hip_bfloat16*)h1, as1, ad1, b1,
                      (__hip_bfloat16*)out1, d, true);
    else    msg1_body(offs, csrc, (const float*)h1, as1, ad1, b1,
                      (float*)out1, d, false);
}

// ---------------- Layer 2 GEMM via MFMA (bf16 mode): out1bf[N,128] @ W2[128,64] ----------------
__global__ __launch_bounds__(256)
void gemm2_mfma_kernel(const __hip_bfloat16* __restrict__ h2b,
                       const void* __restrict__ W2v,
                       const void* __restrict__ a_srcv, const void* __restrict__ a_dstv,
                       __hip_bfloat16* __restrict__ g2b,
                       float* __restrict__ as2, float* __restrict__ ad2,
                       int N, const int* __restrict__ dflag) {
    if (*dflag == 0) return;
    __shared__ __align__(16) unsigned short Bs[64 * 136];
    const unsigned short* Wg = (const unsigned short*)W2v;
    for (int i = threadIdx.x; i < 64 * 64; i += 256) {
        int col = i & 63;
        int k = (i >> 6) * 2;
        unsigned w0 = Wg[k * 64 + col];
        unsigned w1 = Wg[(k + 1) * 64 + col];
        *(unsigned*)&Bs[col * 136 + k] = w0 | (w1 << 16);
    }
    __syncthreads();

    const int lane = threadIdx.x & 63, ww = threadIdx.x >> 6;
    const int quad = lane >> 4, l16 = lane & 15;
    const int nodeBase = blockIdx.x * 64 + ww * 16;
    int arow = nodeBase + l16;
    if (arow >= N) arow = N - 1;
    const short* xp = (const short*)h2b + (size_t)arow * C1 + quad * 8;
    short8 afr[4];
#pragma unroll
    for (int kk = 0; kk < 4; ++kk) afr[kk] = *(const short8*)(xp + kk * 32);

    const __hip_bfloat16* asrc = (const __hip_bfloat16*)a_srcv;
    const __hip_bfloat16* adst = (const __hip_bfloat16*)a_dstv;
    float sacc[4] = {0.f,0.f,0.f,0.f}, dacc[4] = {0.f,0.f,0.f,0.f};
#pragma unroll
    for (int ct = 0; ct < 4; ++ct) {
        floatx4 acc = {0.f, 0.f, 0.f, 0.f};
        const int col = ct * 16 + l16;
        const unsigned short* bbase = &Bs[col * 136 + quad * 8];
#pragma unroll
        for (int kk = 0; kk < 4; ++kk) {
            short8 bfr = *(const short8*)(bbase + kk * 32);
            acc = __builtin_amdgcn_mfma_f32_16x16x32_bf16(afr[kk], bfr, acc, 0, 0, 0);
        }
#pragma unroll
        for (int reg = 0; reg < 4; ++reg) {
            int node = nodeBase + quad * 4 + reg;
            if (node < N) g2b[(size_t)node * C2 + col] = __float2bfloat16(acc[reg]);
        }
        float av = (float)asrc[col];
        float dv = (float)adst[col];
#pragma unroll
        for (int reg = 0; reg < 4; ++reg) {
            float ts = acc[reg] * av;
            float td = acc[reg] * dv;
#pragma unroll
            for (int o = 1; o < 16; o <<= 1) {
                ts += __shfl_xor(ts, o, 64);
                td += __shfl_xor(td, o, 64);
            }
            sacc[reg] += ts;
            dacc[reg] += td;
        }
    }
    if (l16 == 0) {
#pragma unroll
        for (int reg = 0; reg < 4; ++reg) {
            int node = nodeBase + quad * 4 + reg;
            if (node < N) { as2[node] = sacc[reg]; ad2[node] = dacc[reg]; }
        }
    }
}

// ---------------- Layer 2 GEMM vector fallback (fp32 mode) ----------------
__global__ __launch_bounds__(64)
void gemm2_vec_kernel(const float* __restrict__ h2, const float* __restrict__ W2,
                      const float* __restrict__ a_src, const float* __restrict__ a_dst,
                      float* __restrict__ g2, float* __restrict__ as2,
                      float* __restrict__ ad2, int N, const int* __restrict__ dflag) {
    if (*dflag != 0) return;
    __shared__ __align__(16) float xs[8][C1];
    const int t = threadIdx.x;
    const int n0 = blockIdx.x * 8;
#pragma unroll
    for (int j = 0; j < 8; ++j) {
        int n = n0 + j;
        if (n < N) {
            float2 v = *(const float2*)&h2[(size_t)n * C1 + t * 2];
            xs[j][t * 2] = v.x; xs[j][t * 2 + 1] = v.y;
        } else { xs[j][t * 2] = 0.f; xs[j][t * 2 + 1] = 0.f; }
    }
    __syncthreads();
    float acc[8] = {0.f,0.f,0.f,0.f,0.f,0.f,0.f,0.f};
    for (int k = 0; k < 128; k += 4) {
        float w0 = W2[(k + 0) * C2 + t], w1 = W2[(k + 1) * C2 + t];
        float w2 = W2[(k + 2) * C2 + t], w3 = W2[(k + 3) * C2 + t];
#pragma unroll
        for (int j = 0; j < 8; ++j) {
            float4 xv = *(const float4*)&xs[j][k];
            acc[j] += xv.x * w0 + xv.y * w1 + xv.z * w2 + xv.w * w3;
        }
    }
    const float asv = a_src[t];
    const float adv = a_dst[t];
#pragma unroll
    for (int j = 0; j < 8; ++j) {
        int n = n0 + j;
        if (n < N) g2[(size_t)n * C2 + t] = acc[j];
        float ps = acc[j] * asv;
        float pd = acc[j] * adv;
#pragma unroll
        for (int o = 32; o >= 1; o >>= 1) {
            ps += __shfl_xor(ps, o, 64);
            pd += __shfl_xor(pd, o, 64);
        }
        if (t == 0 && n < N) { as2[n] = ps; ad2[n] = pd; }
    }
}

// ---------------- Layer 2 CSR gather (4-deep strip-mine) + bias + store ----------------
template <typename HT>
__device__ __forceinline__ void msg2_body(const int* __restrict__ offs,
                                          const int* __restrict__ csrc,
                                          const HT* __restrict__ g2,
                                          const float* __restrict__ as2,
                                          const float* __restrict__ ad2,
                                          const void* __restrict__ b2,
                                          void* __restrict__ y, int d, bool bf) {
    const int lane = threadIdx.x & 63;
    const int beg = offs[d], end = offs[d + 1];
    const float add = ad2[d];
    float acc = 0.f, sumw = 0.f;
    for (int jj = beg; jj < end; jj += 4) {
        int i1 = jj + 1 < end ? jj + 1 : end - 1;
        int i2 = jj + 2 < end ? jj + 2 : end - 1;
        int i3 = jj + 3 < end ? jj + 3 : end - 1;
        int s0 = csrc[jj], s1 = csrc[i1], s2 = csrc[i2], s3 = csrc[i3];
        float a0 = as2[s0], a1 = as2[s1], a2 = as2[s2], a3 = as2[s3];
        float v0 = ldh(g2, (size_t)s0 * C2 + lane), v1 = ldh(g2, (size_t)s1 * C2 + lane);
        float v2 = ldh(g2, (size_t)s2 * C2 + lane), v3 = ldh(g2, (size_t)s3 * C2 + lane);
        float w0 = __expf(lrelu(a0 + add));
        float w1 = (jj + 1 < end) ? __expf(lrelu(a1 + add)) : 0.f;
        float w2 = (jj + 2 < end) ? __expf(lrelu(a2 + add)) : 0.f;
        float w3 = (jj + 3 < end) ? __expf(lrelu(a3 + add)) : 0.f;
        sumw += (w0 + w1) + (w2 + w3);
        acc += w0 * v0 + w1 * v1 + w2 * v2 + w3 * v3;
    }
    float m = (sumw > 0.f) ? acc / sumw : 0.f;
    float v = m + ldin(b2, lane, bf);
    if (bf) ((__hip_bfloat16*)y)[(size_t)d * C2 + lane] = __float2bfloat16(v);
    else    ((float*)y)[(size_t)d * C2 + lane] = v;
}

__global__ __launch_bounds__(256)
void msg2_csr_kernel(const int* __restrict__ offs, const int* __restrict__ csrc,
                     const void* __restrict__ g2, const float* __restrict__ as2,
                     const float* __restrict__ ad2, const void* __restrict__ b2,
                     void* __restrict__ y, int N, const int* __restrict__ dflag) {
    const bool bf = (*dflag != 0);
    const int d = blockIdx.x * 4 + (threadIdx.x >> 6);
    if (d >= N) return;
    if (bf) msg2_body(offs, csrc, (const __hip_bfloat16*)g2, as2, ad2, b2, y, d, true);
    else    msg2_body(offs, csrc, (const float*)g2,          as2, ad2, b2, y, d, false);
}

extern "C" void kernel_launch(void* const* d_in, const int* in_sizes, int n_in,
                              void* d_out, int out_size, void* d_ws, size_t ws_size,
                              hipStream_t stream) {
    const void* x    = d_in[0];
    const int*  ei   = (const int*)d_in[1];
    const void* W1   = d_in[2];
    const void* a_s1 = d_in[3];
    const void* a_d1 = d_in[4];
    const void* b1   = d_in[5];
    const void* W2   = d_in[6];
    const void* a_s2 = d_in[7];
    const void* a_d2 = d_in[8];
    const void* b2   = d_in[9];

    const int N = in_sizes[0] / C1;
    const int E = in_sizes[1] / 2;

    auto align16 = [](size_t v) { return (v + 15) & ~(size_t)15; };
    const size_t RF   = 16;
    const size_t ROFF = align16((size_t)(N + 1) * 4);
    const size_t RCUR = align16((size_t)N * 4);
    const size_t RBS  = 256;
    const size_t RSRC = align16((size_t)E * 4);
    const size_t R1   = align16((size_t)N * C1 * 4);   // h1/g2 (fp32 worst case)
    const size_t R2   = align16((size_t)N * 8 * 4);    // as1+ad1 / as2+ad2

    char* base = (char*)d_ws;
    int*  dflag  = (int*)base;
    int*  offs   = (int*)(base + RF);
    int*  cursor = (int*)(base + RF + ROFF);
    int*  bsum   = (int*)(base + RF + ROFF + RCUR);
    int*  csrc   = (int*)(base + RF + ROFF + RCUR + RBS);
    char* R1p = base + RF + ROFF + RCUR + RBS + RSRC;
    char* R2p = R1p + R1;
    char* R4p = R2p + R2;
    (void)ws_size;

    void*  h1  = (void*)R1p;       // bf16 (bf mode) or fp32 (fallback)
    void*  g2  = (void*)R1p;       // h1 dead after msg1
    float* as1 = (float*)R2p;
    float* ad1 = as1 + (size_t)N * 4;
    float* as2 = (float*)R2p;
    float* ad2 = as2 + N;
    void*  out1 = (void*)R4p;      // bf16 (bf mode) or fp32 (fallback)

    const int nbScan = (N + 1023) / 1024;
    const int nbTile = (N + 63) / 64;

    detect_kernel<<<1, 256, 0, stream>>>((const unsigned*)x, 2048, dflag);
    hipMemsetAsync(cursor, 0, (size_t)N * 4, stream);
    count_kernel<<<1024, 256, 0, stream>>>(ei, cursor, N, E);
    scanA_kernel<<<nbScan, 1024, 0, stream>>>(cursor, offs, bsum, N);
    scanB_kernel<<<1, 64, 0, stream>>>(bsum, &offs[N], nbScan);
    scanC_kernel<<<nbScan, 1024, 0, stream>>>(offs, cursor, bsum, N);
    fill_kernel<<<1024, 256, 0, stream>>>(ei, cursor, csrc, N, E);

    gemm1_mfma_kernel<<<nbTile, 256, 0, stream>>>(x, W1, a_s1, a_d1,
        (__hip_bfloat16*)h1, as1, ad1, N, dflag);
    gemm1_vec_kernel<<<(N + 7) / 8, 128, 0, stream>>>((const float*)x, (const float*)W1,
        (const float*)a_s1, (const float*)a_d1, (float*)h1, as1, ad1, N, dflag);

    msg1_csr_kernel<<<N, 128, 0, stream>>>(offs, csrc, h1, as1, ad1, b1, out1, N, dflag);

    gemm2_mfma_kernel<<<nbTile, 256, 0, stream>>>((const __hip_bfloat16*)out1, W2,
        a_s2, a_d2, (__hip_bfloat16*)g2, as2, ad2, N, dflag);
    gemm2_vec_kernel<<<(N + 7) / 8, 64, 0, stream>>>((const float*)out1, (const float*)W2,
        (const float*)a_s2, (const float*)a_d2, (float*)g2, as2, ad2, N, dflag);

    msg2_csr_kernel<<<(N + 3) / 4, 256, 0, stream>>>(offs, csrc, g2, as2, ad2, b2, d_out, N, dflag);
}

// Round 7
// 373.304 us; speedup vs baseline: 2.7627x; 1.0402x over previous
//
#include <hip/hip_runtime.h>
#include <hip/hip_bf16.h>

#define C1 128   // heads1(4) * hid(32)
#define C2 64    // out channels layer 2

typedef __attribute__((ext_vector_type(8))) short short8;
typedef __attribute__((ext_vector_type(4))) float floatx4;

__device__ __forceinline__ float lrelu(float v) { return v > 0.f ? v : 0.2f * v; }

__device__ __forceinline__ float ldin(const void* p, size_t i, bool bf) {
    return bf ? (float)((const __hip_bfloat16*)p)[i] : ((const float*)p)[i];
}
__device__ __forceinline__ float ldh(const float* p, size_t i) { return p[i]; }
__device__ __forceinline__ float ldh(const __hip_bfloat16* p, size_t i) { return (float)p[i]; }
__device__ __forceinline__ void stout(float* p, size_t i, float v) { p[i] = v; }
__device__ __forceinline__ void stout(__hip_bfloat16* p, size_t i, float v) { p[i] = __float2bfloat16(v); }

// ---------------- dtype detection (bf16 vs fp32 inputs) ----------------
__global__ __launch_bounds__(256)
void detect_kernel(const unsigned* __restrict__ xw, int nwords, int* __restrict__ flag) {
    __shared__ int cnt;
    if (threadIdx.x == 0) cnt = 0;
    __syncthreads();
    int my = 0;
    for (int i = threadIdx.x; i < nwords; i += 256) {
        unsigned lo = xw[i] & 0xFFFFu;
        int e = (lo >> 7) & 0xFF;
        if (e >= 110 && e <= 140) ++my;
    }
    atomicAdd(&cnt, my);
    __syncthreads();
    if (threadIdx.x == 0) *flag = (cnt * 2 > nwords) ? 1 : 0;
}

// ---------------- CSR build ----------------
__global__ __launch_bounds__(256)
void count_kernel(const int* __restrict__ ei, int* __restrict__ deg, int N, int E) {
    for (int e = blockIdx.x * blockDim.x + threadIdx.x; e < E;
         e += gridDim.x * blockDim.x) {
        int d = ei[E + e];
        if ((unsigned)d < (unsigned)N) atomicAdd(&deg[d], 1);
    }
}

__global__ __launch_bounds__(1024)
void scanA_kernel(const int* __restrict__ deg, int* __restrict__ offs,
                  int* __restrict__ bsum, int N) {
    __shared__ int wsum[16];
    const int i = blockIdx.x * 1024 + threadIdx.x;
    const int lane = threadIdx.x & 63, wid = threadIdx.x >> 6;
    int v = (i < N) ? deg[i] : 0;
    int x = v;
#pragma unroll
    for (int o = 1; o < 64; o <<= 1) {
        int y = __shfl_up(x, o, 64);
        if (lane >= o) x += y;
    }
    if (lane == 63) wsum[wid] = x;
    __syncthreads();
    if (wid == 0 && lane < 16) {
        int s = wsum[lane];
#pragma unroll
        for (int o = 1; o < 16; o <<= 1) {
            int y = __shfl_up(s, o, 16);
            if (lane >= o) s += y;
        }
        wsum[lane] = s;
    }
    __syncthreads();
    int pre = (wid > 0) ? wsum[wid - 1] : 0;
    int incl = x + pre;
    if (i < N) offs[i] = incl - v;
    if (threadIdx.x == 1023) bsum[blockIdx.x] = incl;
}

__global__ __launch_bounds__(64)
void scanB_kernel(int* __restrict__ bsum, int* __restrict__ offs_end, int nb) {
    const int lane = threadIdx.x;
    if (nb <= 64) {
        int v = (lane < nb) ? bsum[lane] : 0;
        int x = v;
#pragma unroll
        for (int o = 1; o < 64; o <<= 1) {
            int y = __shfl_up(x, o, 64);
            if (lane >= o) x += y;
        }
        if (lane < nb) bsum[lane] = x - v;
        int tot = __shfl(x, 63, 64);
        if (lane == 0) *offs_end = tot;
    } else if (lane == 0) {
        int run = 0;
        for (int b = 0; b < nb; ++b) { int t = bsum[b]; bsum[b] = run; run += t; }
        *offs_end = run;
    }
}

__global__ __launch_bounds__(1024)
void scanC_kernel(int* __restrict__ offs, int* __restrict__ cursor,
                  const int* __restrict__ bsum, int N) {
    const int i = blockIdx.x * 1024 + threadIdx.x;
    if (i < N) {
        int o = offs[i] + bsum[blockIdx.x];
        offs[i] = o;
        cursor[i] = o;
    }
}

__global__ __launch_bounds__(256)
void fill_kernel(const int* __restrict__ ei, int* __restrict__ cursor,
                 int* __restrict__ csrc, int N, int E) {
    for (int e = blockIdx.x * blockDim.x + threadIdx.x; e < E;
         e += gridDim.x * blockDim.x) {
        int s = ei[e], d = ei[E + e];
        if ((unsigned)s >= (unsigned)N || (unsigned)d >= (unsigned)N) continue;
        int pos = atomicAdd(&cursor[d], 1);
        csrc[pos] = s;
    }
}

// ---------------- Layer 1 GEMM via MFMA (bf16 mode) ----------------
__global__ __launch_bounds__(256)
void gemm1_mfma_kernel(const void* __restrict__ xv, const void* __restrict__ W1v,
                       const void* __restrict__ a_srcv, const void* __restrict__ a_dstv,
                       __hip_bfloat16* __restrict__ h1b,
                       float* __restrict__ as1, float* __restrict__ ad1,
                       int N, const int* __restrict__ dflag) {
    if (*dflag == 0) return;
    __shared__ __align__(16) unsigned short Bs[128 * 136];
    const unsigned short* Wg = (const unsigned short*)W1v;
    for (int i = threadIdx.x; i < 128 * 64; i += 256) {
        int col = i & 127;
        int k = (i >> 7) * 2;
        unsigned w0 = Wg[k * 128 + col];
        unsigned w1 = Wg[(k + 1) * 128 + col];
        *(unsigned*)&Bs[col * 136 + k] = w0 | (w1 << 16);
    }
    __syncthreads();

    const int lane = threadIdx.x & 63, ww = threadIdx.x >> 6;
    const int quad = lane >> 4, l16 = lane & 15;
    const int nodeBase = blockIdx.x * 64 + ww * 16;
    int arow = nodeBase + l16;
    if (arow >= N) arow = N - 1;
    const short* xp = (const short*)xv + (size_t)arow * C1 + quad * 8;
    short8 afr[4];
#pragma unroll
    for (int kk = 0; kk < 4; ++kk) afr[kk] = *(const short8*)(xp + kk * 32);

    const __hip_bfloat16* asrc = (const __hip_bfloat16*)a_srcv;
    const __hip_bfloat16* adst = (const __hip_bfloat16*)a_dstv;
    float sacc[4], dacc[4];
#pragma unroll
    for (int ct = 0; ct < 8; ++ct) {
        floatx4 acc = {0.f, 0.f, 0.f, 0.f};
        const int col = ct * 16 + l16;
        const unsigned short* bbase = &Bs[col * 136 + quad * 8];
#pragma unroll
        for (int kk = 0; kk < 4; ++kk) {
            short8 bfr = *(const short8*)(bbase + kk * 32);
            acc = __builtin_amdgcn_mfma_f32_16x16x32_bf16(afr[kk], bfr, acc, 0, 0, 0);
        }
#pragma unroll
        for (int reg = 0; reg < 4; ++reg) {
            int node = nodeBase + quad * 4 + reg;
            if (node < N) h1b[(size_t)node * C1 + col] = __float2bfloat16(acc[reg]);
        }
        float av = (float)asrc[col];
        float dv = (float)adst[col];
        if ((ct & 1) == 0) {
#pragma unroll
            for (int r = 0; r < 4; ++r) { sacc[r] = 0.f; dacc[r] = 0.f; }
        }
#pragma unroll
        for (int reg = 0; reg < 4; ++reg) {
            float ts = acc[reg] * av;
            float td = acc[reg] * dv;
#pragma unroll
            for (int o = 1; o < 16; o <<= 1) {
                ts += __shfl_xor(ts, o, 64);
                td += __shfl_xor(td, o, 64);
            }
            sacc[reg] += ts;
            dacc[reg] += td;
        }
        if ((ct & 1) == 1 && l16 == 0) {
            int h = ct >> 1;
#pragma unroll
            for (int reg = 0; reg < 4; ++reg) {
                int node = nodeBase + quad * 4 + reg;
                if (node < N) {
                    as1[node * 4 + h] = sacc[reg];
                    ad1[node * 4 + h] = dacc[reg];
                }
            }
        }
    }
}

// ---------------- Layer 1 GEMM vector fallback (fp32 inputs) ----------------
__global__ __launch_bounds__(128)
void gemm1_vec_kernel(const float* __restrict__ x, const float* __restrict__ W1,
                      const float* __restrict__ a_src, const float* __restrict__ a_dst,
                      float* __restrict__ h1, float* __restrict__ as1,
                      float* __restrict__ ad1, int N, const int* __restrict__ dflag) {
    if (*dflag != 0) return;
    __shared__ float xs[8][C1];
    const int t = threadIdx.x;
    const int n0 = blockIdx.x * 8;
#pragma unroll
    for (int j = 0; j < 8; ++j) {
        int n = n0 + j;
        xs[j][t] = (n < N) ? x[(size_t)n * C1 + t] : 0.f;
    }
    __syncthreads();
    float acc[8] = {0.f,0.f,0.f,0.f,0.f,0.f,0.f,0.f};
    for (int k = 0; k < 128; ++k) {
        float wv = W1[k * C1 + t];
#pragma unroll
        for (int j = 0; j < 8; ++j) acc[j] += xs[j][k] * wv;
    }
    const float asv = a_src[t];
    const float adv = a_dst[t];
    const int head = t >> 5;
#pragma unroll
    for (int j = 0; j < 8; ++j) {
        int n = n0 + j;
        if (n < N) h1[(size_t)n * C1 + t] = acc[j];
        float ps = acc[j] * asv;
        float pd = acc[j] * adv;
#pragma unroll
        for (int o = 16; o >= 1; o >>= 1) {
            ps += __shfl_xor(ps, o, 32);
            pd += __shfl_xor(pd, o, 32);
        }
        if ((t & 31) == 0 && n < N) {
            as1[n * 4 + head] = ps;
            ad1[n * 4 + head] = pd;
        }
    }
}

// ---------------- Layer 1 CSR gather (strip-8, shfl-broadcast weights) ----------------
template <typename HT, typename OT>
__device__ __forceinline__ void msg1_body(const int* __restrict__ offs,
                                          const int* __restrict__ csrc,
                                          const HT* __restrict__ h1,
                                          const float* __restrict__ as1,
                                          const float* __restrict__ ad1,
                                          const void* __restrict__ b1,
                                          OT* __restrict__ out1,
                                          int d, bool bf) {
    const int t = threadIdx.x;        // 0..127; col = t
    const int lane = t & 63;
    const int wv = t >> 6;            // wave 0/1
    const int beg = offs[d], end = offs[d + 1];
    // weight-lane roles (lanes 0..15 of each wave): k = lane&7, head-group = lane>>3
    const int wk = lane & 7;
    const int whead = wv * 2 + ((lane >> 3) & 1);
    const float wadh = ad1[d * 4 + whead];
    const int myHg = lane >> 5;       // consuming head-group within wave
    float acc = 0.f, sumw = 0.f;
    for (int jj = beg; jj < end; jj += 8) {
        int idx = jj + (lane & 7);
        if (idx >= end) idx = end - 1;
        const int myS = csrc[idx];
        int s[8];
#pragma unroll
        for (int k = 0; k < 8; ++k) s[k] = __shfl(myS, k, 64);
        float v[8];
#pragma unroll
        for (int k = 0; k < 8; ++k) v[k] = ldh(h1, (size_t)s[k] * C1 + t);
        float w = 0.f;
        if (lane < 16) {
            float a = as1[s[wk] * 4 + whead];
            if (jj + wk < end) w = __expf(lrelu(a + wadh));
        }
#pragma unroll
        for (int k = 0; k < 8; ++k) {
            float wkv = __shfl(w, myHg * 8 + k, 64);
            sumw += wkv;
            acc += wkv * v[k];
        }
    }
    float m = (sumw > 0.f) ? acc / sumw : 0.f;
    float vv = m + ldin(b1, t, bf);
    stout(out1, (size_t)d * C1 + t, vv > 0.f ? vv : expm1f(vv));
}

__global__ __launch_bounds__(128)
void msg1_csr_kernel(const int* __restrict__ offs, const int* __restrict__ csrc,
                     const void* __restrict__ h1, const float* __restrict__ as1,
                     const float* __restrict__ ad1, const void* __restrict__ b1,
                     void* __restrict__ out1, int N, const int* __restrict__ dflag) {
    const bool bf = (*dflag != 0);
    const int d = blockIdx.x;
    if (d >= N) return;
    if (bf) msg1_body(offs, csrc, (const __hip_bfloat16*)h1, as1, ad1, b1,
                      (__hip_bfloat16*)out1, d, true);
    else    msg1_body(offs, csrc, (const float*)h1, as1, ad1, b1,
                      (float*)out1, d, false);
}

// ---------------- Layer 2 GEMM via MFMA (bf16 mode) ----------------
__global__ __launch_bounds__(256)
void gemm2_mfma_kernel(const __hip_bfloat16* __restrict__ h2b,
                       const void* __restrict__ W2v,
                       const void* __restrict__ a_srcv, const void* __restrict__ a_dstv,
                       __hip_bfloat16* __restrict__ g2b,
                       float* __restrict__ as2, float* __restrict__ ad2,
                       int N, const int* __restrict__ dflag) {
    if (*dflag == 0) return;
    __shared__ __align__(16) unsigned short Bs[64 * 136];
    const unsigned short* Wg = (const unsigned short*)W2v;
    for (int i = threadIdx.x; i < 64 * 64; i += 256) {
        int col = i & 63;
        int k = (i >> 6) * 2;
        unsigned w0 = Wg[k * 64 + col];
        unsigned w1 = Wg[(k + 1) * 64 + col];
        *(unsigned*)&Bs[col * 136 + k] = w0 | (w1 << 16);
    }
    __syncthreads();

    const int lane = threadIdx.x & 63, ww = threadIdx.x >> 6;
    const int quad = lane >> 4, l16 = lane & 15;
    const int nodeBase = blockIdx.x * 64 + ww * 16;
    int arow = nodeBase + l16;
    if (arow >= N) arow = N - 1;
    const short* xp = (const short*)h2b + (size_t)arow * C1 + quad * 8;
    short8 afr[4];
#pragma unroll
    for (int kk = 0; kk < 4; ++kk) afr[kk] = *(const short8*)(xp + kk * 32);

    const __hip_bfloat16* asrc = (const __hip_bfloat16*)a_srcv;
    const __hip_bfloat16* adst = (const __hip_bfloat16*)a_dstv;
    float sacc[4] = {0.f,0.f,0.f,0.f}, dacc[4] = {0.f,0.f,0.f,0.f};
#pragma unroll
    for (int ct = 0; ct < 4; ++ct) {
        floatx4 acc = {0.f, 0.f, 0.f, 0.f};
        const int col = ct * 16 + l16;
        const unsigned short* bbase = &Bs[col * 136 + quad * 8];
#pragma unroll
        for (int kk = 0; kk < 4; ++kk) {
            short8 bfr = *(const short8*)(bbase + kk * 32);
            acc = __builtin_amdgcn_mfma_f32_16x16x32_bf16(afr[kk], bfr, acc, 0, 0, 0);
        }
#pragma unroll
        for (int reg = 0; reg < 4; ++reg) {
            int node = nodeBase + quad * 4 + reg;
            if (node < N) g2b[(size_t)node * C2 + col] = __float2bfloat16(acc[reg]);
        }
        float av = (float)asrc[col];
        float dv = (float)adst[col];
#pragma unroll
        for (int reg = 0; reg < 4; ++reg) {
            float ts = acc[reg] * av;
            float td = acc[reg] * dv;
#pragma unroll
            for (int o = 1; o < 16; o <<= 1) {
                ts += __shfl_xor(ts, o, 64);
                td += __shfl_xor(td, o, 64);
            }
            sacc[reg] += ts;
            dacc[reg] += td;
        }
    }
    if (l16 == 0) {
#pragma unroll
        for (int reg = 0; reg < 4; ++reg) {
            int node = nodeBase + quad * 4 + reg;
            if (node < N) { as2[node] = sacc[reg]; ad2[node] = dacc[reg]; }
        }
    }
}

// ---------------- Layer 2 GEMM vector fallback (fp32 mode) ----------------
__global__ __launch_bounds__(64)
void gemm2_vec_kernel(const float* __restrict__ h2, const float* __restrict__ W2,
                      const float* __restrict__ a_src, const float* __restrict__ a_dst,
                      float* __restrict__ g2, float* __restrict__ as2,
                      float* __restrict__ ad2, int N, const int* __restrict__ dflag) {
    if (*dflag != 0) return;
    __shared__ __align__(16) float xs[8][C1];
    const int t = threadIdx.x;
    const int n0 = blockIdx.x * 8;
#pragma unroll
    for (int j = 0; j < 8; ++j) {
        int n = n0 + j;
        if (n < N) {
            float2 v = *(const float2*)&h2[(size_t)n * C1 + t * 2];
            xs[j][t * 2] = v.x; xs[j][t * 2 + 1] = v.y;
        } else { xs[j][t * 2] = 0.f; xs[j][t * 2 + 1] = 0.f; }
    }
    __syncthreads();
    float acc[8] = {0.f,0.f,0.f,0.f,0.f,0.f,0.f,0.f};
    for (int k = 0; k < 128; k += 4) {
        float w0 = W2[(k + 0) * C2 + t], w1 = W2[(k + 1) * C2 + t];
        float w2 = W2[(k + 2) * C2 + t], w3 = W2[(k + 3) * C2 + t];
#pragma unroll
        for (int j = 0; j < 8; ++j) {
            float4 xv = *(const float4*)&xs[j][k];
            acc[j] += xv.x * w0 + xv.y * w1 + xv.z * w2 + xv.w * w3;
        }
    }
    const float asv = a_src[t];
    const float adv = a_dst[t];
#pragma unroll
    for (int j = 0; j < 8; ++j) {
        int n = n0 + j;
        if (n < N) g2[(size_t)n * C2 + t] = acc[j];
        float ps = acc[j] * asv;
        float pd = acc[j] * adv;
#pragma unroll
        for (int o = 32; o >= 1; o >>= 1) {
            ps += __shfl_xor(ps, o, 64);
            pd += __shfl_xor(pd, o, 64);
        }
        if (t == 0 && n < N) { as2[n] = ps; ad2[n] = pd; }
    }
}

// ---------------- Layer 2 CSR gather (strip-8, shfl-broadcast weights) ----------------
template <typename HT>
__device__ __forceinline__ void msg2_body(const int* __restrict__ offs,
                                          const int* __restrict__ csrc,
                                          const HT* __restrict__ g2,
                                          const float* __restrict__ as2,
                                          const float* __restrict__ ad2,
                                          const void* __restrict__ b2,
                                          void* __restrict__ y, int d, bool bf) {
    const int lane = threadIdx.x & 63;
    const int beg = offs[d], end = offs[d + 1];
    const float add = ad2[d];
    float acc = 0.f, sumw = 0.f;
    for (int jj = beg; jj < end; jj += 8) {
        int idx = jj + (lane & 7);
        if (idx >= end) idx = end - 1;
        const int myS = csrc[idx];
        int s[8];
#pragma unroll
        for (int k = 0; k < 8; ++k) s[k] = __shfl(myS, k, 64);
        float v[8];
#pragma unroll
        for (int k = 0; k < 8; ++k) v[k] = ldh(g2, (size_t)s[k] * C2 + lane);
        float w = 0.f;
        if (lane < 8) {
            float a = as2[myS];
            if (jj + lane < end) w = __expf(lrelu(a + add));
        }
#pragma unroll
        for (int k = 0; k < 8; ++k) {
            float wkv = __shfl(w, k, 64);
            sumw += wkv;
            acc += wkv * v[k];
        }
    }
    float m = (sumw > 0.f) ? acc / sumw : 0.f;
    float v = m + ldin(b2, lane, bf);
    if (bf) ((__hip_bfloat16*)y)[(size_t)d * C2 + lane] = __float2bfloat16(v);
    else    ((float*)y)[(size_t)d * C2 + lane] = v;
}

__global__ __launch_bounds__(256)
void msg2_csr_kernel(const int* __restrict__ offs, const int* __restrict__ csrc,
                     const void* __restrict__ g2, const float* __restrict__ as2,
                     const float* __restrict__ ad2, const void* __restrict__ b2,
                     void* __restrict__ y, int N, const int* __restrict__ dflag) {
    const bool bf = (*dflag != 0);
    const int d = blockIdx.x * 4 + (threadIdx.x >> 6);
    if (d >= N) return;
    if (bf) msg2_body(offs, csrc, (const __hip_bfloat16*)g2, as2, ad2, b2, y, d, true);
    else    msg2_body(offs, csrc, (const float*)g2,          as2, ad2, b2, y, d, false);
}

extern "C" void kernel_launch(void* const* d_in, const int* in_sizes, int n_in,
                              void* d_out, int out_size, void* d_ws, size_t ws_size,
                              hipStream_t stream) {
    const void* x    = d_in[0];
    const int*  ei   = (const int*)d_in[1];
    const void* W1   = d_in[2];
    const void* a_s1 = d_in[3];
    const void* a_d1 = d_in[4];
    const void* b1   = d_in[5];
    const void* W2   = d_in[6];
    const void* a_s2 = d_in[7];
    const void* a_d2 = d_in[8];
    const void* b2   = d_in[9];

    const int N = in_sizes[0] / C1;
    const int E = in_sizes[1] / 2;

    auto align16 = [](size_t v) { return (v + 15) & ~(size_t)15; };
    const size_t RF   = 16;
    const size_t ROFF = align16((size_t)(N + 1) * 4);
    const size_t RCUR = align16((size_t)N * 4);
    const size_t RBS  = 256;
    const size_t RSRC = align16((size_t)E * 4);
    const size_t R1   = align16((size_t)N * C1 * 4);   // h1/g2 (fp32 worst case)
    const size_t R2   = align16((size_t)N * 8 * 4);    // as1+ad1 / as2+ad2

    char* base = (char*)d_ws;
    int*  dflag  = (int*)base;
    int*  offs   = (int*)(base + RF);
    int*  cursor = (int*)(base + RF + ROFF);
    int*  bsum   = (int*)(base + RF + ROFF + RCUR);
    int*  csrc   = (int*)(base + RF + ROFF + RCUR + RBS);
    char* R1p = base + RF + ROFF + RCUR + RBS + RSRC;
    char* R2p = R1p + R1;
    char* R4p = R2p + R2;
    (void)ws_size;

    void*  h1  = (void*)R1p;
    void*  g2  = (void*)R1p;
    float* as1 = (float*)R2p;
    float* ad1 = as1 + (size_t)N * 4;
    float* as2 = (float*)R2p;
    float* ad2 = as2 + N;
    void*  out1 = (void*)R4p;

    const int nbScan = (N + 1023) / 1024;
    const int nbTile = (N + 63) / 64;

    detect_kernel<<<1, 256, 0, stream>>>((const unsigned*)x, 2048, dflag);
    hipMemsetAsync(cursor, 0, (size_t)N * 4, stream);
    count_kernel<<<1024, 256, 0, stream>>>(ei, cursor, N, E);
    scanA_kernel<<<nbScan, 1024, 0, stream>>>(cursor, offs, bsum, N);
    scanB_kernel<<<1, 64, 0, stream>>>(bsum, &offs[N], nbScan);
    scanC_kernel<<<nbScan, 1024, 0, stream>>>(offs, cursor, bsum, N);
    fill_kernel<<<1024, 256, 0, stream>>>(ei, cursor, csrc, N, E);

    gemm1_mfma_kernel<<<nbTile, 256, 0, stream>>>(x, W1, a_s1, a_d1,
        (__hip_bfloat16*)h1, as1, ad1, N, dflag);
    gemm1_vec_kernel<<<(N + 7) / 8, 128, 0, stream>>>((const float*)x, (const float*)W1,
        (const float*)a_s1, (const float*)a_d1, (float*)h1, as1, ad1, N, dflag);

    msg1_csr_kernel<<<N, 128, 0, stream>>>(offs, csrc, h1, as1, ad1, b1, out1, N, dflag);

    gemm2_mfma_kernel<<<nbTile, 256, 0, stream>>>((const __hip_bfloat16*)out1, W2,
        a_s2, a_d2, (__hip_bfloat16*)g2, as2, ad2, N, dflag);
    gemm2_vec_kernel<<<(N + 7) / 8, 64, 0, stream>>>((const float*)out1, (const float*)W2,
        (const float*)a_s2, (const float*)a_d2, (float*)g2, as2, ad2, N, dflag);

    msg2_csr_kernel<<<(N + 3) / 4, 256, 0, stream>>>(offs, csrc, g2, as2, ad2, b2, d_out, N, dflag);
}

// Round 8
// 373.108 us; speedup vs baseline: 2.7641x; 1.0005x over previous
//
#include <hip/hip_runtime.h>
#include <hip/hip_bf16.h>

#define C1 128   // heads1(4) * hid(32)
#define C2 64    // out channels layer 2

typedef __attribute__((ext_vector_type(8))) short short8;
typedef __attribute__((ext_vector_type(4))) float floatx4;

__device__ __forceinline__ float lrelu(float v) { return v > 0.f ? v : 0.2f * v; }

__device__ __forceinline__ float ldin(const void* p, size_t i, bool bf) {
    return bf ? (float)((const __hip_bfloat16*)p)[i] : ((const float*)p)[i];
}

// ---------------- dtype detection (bf16 vs fp32 inputs) ----------------
__global__ __launch_bounds__(256)
void detect_kernel(const unsigned* __restrict__ xw, int nwords, int* __restrict__ flag) {
    __shared__ int cnt;
    if (threadIdx.x == 0) cnt = 0;
    __syncthreads();
    int my = 0;
    for (int i = threadIdx.x; i < nwords; i += 256) {
        unsigned lo = xw[i] & 0xFFFFu;
        int e = (lo >> 7) & 0xFF;
        if (e >= 110 && e <= 140) ++my;
    }
    atomicAdd(&cnt, my);
    __syncthreads();
    if (threadIdx.x == 0) *flag = (cnt * 2 > nwords) ? 1 : 0;
}

// ---------------- CSR build ----------------
__global__ __launch_bounds__(256)
void count_kernel(const int* __restrict__ ei, int* __restrict__ deg, int N, int E) {
    for (int e = blockIdx.x * blockDim.x + threadIdx.x; e < E;
         e += gridDim.x * blockDim.x) {
        int d = ei[E + e];
        if ((unsigned)d < (unsigned)N) atomicAdd(&deg[d], 1);
    }
}

__global__ __launch_bounds__(1024)
void scanA_kernel(const int* __restrict__ deg, int* __restrict__ offs,
                  int* __restrict__ bsum, int N) {
    __shared__ int wsum[16];
    const int i = blockIdx.x * 1024 + threadIdx.x;
    const int lane = threadIdx.x & 63, wid = threadIdx.x >> 6;
    int v = (i < N) ? deg[i] : 0;
    int x = v;
#pragma unroll
    for (int o = 1; o < 64; o <<= 1) {
        int y = __shfl_up(x, o, 64);
        if (lane >= o) x += y;
    }
    if (lane == 63) wsum[wid] = x;
    __syncthreads();
    if (wid == 0 && lane < 16) {
        int s = wsum[lane];
#pragma unroll
        for (int o = 1; o < 16; o <<= 1) {
            int y = __shfl_up(s, o, 16);
            if (lane >= o) s += y;
        }
        wsum[lane] = s;
    }
    __syncthreads();
    int pre = (wid > 0) ? wsum[wid - 1] : 0;
    int incl = x + pre;
    if (i < N) offs[i] = incl - v;
    if (threadIdx.x == 1023) bsum[blockIdx.x] = incl;
}

__global__ __launch_bounds__(64)
void scanB_kernel(int* __restrict__ bsum, int* __restrict__ offs_end, int nb) {
    const int lane = threadIdx.x;
    if (nb <= 64) {
        int v = (lane < nb) ? bsum[lane] : 0;
        int x = v;
#pragma unroll
        for (int o = 1; o < 64; o <<= 1) {
            int y = __shfl_up(x, o, 64);
            if (lane >= o) x += y;
        }
        if (lane < nb) bsum[lane] = x - v;
        int tot = __shfl(x, 63, 64);
        if (lane == 0) *offs_end = tot;
    } else if (lane == 0) {
        int run = 0;
        for (int b = 0; b < nb; ++b) { int t = bsum[b]; bsum[b] = run; run += t; }
        *offs_end = run;
    }
}

__global__ __launch_bounds__(1024)
void scanC_kernel(int* __restrict__ offs, int* __restrict__ cursor,
                  const int* __restrict__ bsum, int N) {
    const int i = blockIdx.x * 1024 + threadIdx.x;
    if (i < N) {
        int o = offs[i] + bsum[blockIdx.x];
        offs[i] = o;
        cursor[i] = o;
    }
}

__global__ __launch_bounds__(256)
void fill_kernel(const int* __restrict__ ei, int* __restrict__ cursor,
                 int* __restrict__ csrc, int N, int E) {
    for (int e = blockIdx.x * blockDim.x + threadIdx.x; e < E;
         e += gridDim.x * blockDim.x) {
        int s = ei[e], d = ei[E + e];
        if ((unsigned)s >= (unsigned)N || (unsigned)d >= (unsigned)N) continue;
        int pos = atomicAdd(&cursor[d], 1);
        csrc[pos] = s;
    }
}

// ---------------- Layer 1 GEMM via MFMA (bf16 mode) ----------------
__global__ __launch_bounds__(256)
void gemm1_mfma_kernel(const void* __restrict__ xv, const void* __restrict__ W1v,
                       const void* __restrict__ a_srcv, const void* __restrict__ a_dstv,
                       __hip_bfloat16* __restrict__ h1b,
                       float* __restrict__ as1, float* __restrict__ ad1,
                       int N, const int* __restrict__ dflag) {
    if (*dflag == 0) return;
    __shared__ __align__(16) unsigned short Bs[128 * 136];
    const unsigned short* Wg = (const unsigned short*)W1v;
    for (int i = threadIdx.x; i < 128 * 64; i += 256) {
        int col = i & 127;
        int k = (i >> 7) * 2;
        unsigned w0 = Wg[k * 128 + col];
        unsigned w1 = Wg[(k + 1) * 128 + col];
        *(unsigned*)&Bs[col * 136 + k] = w0 | (w1 << 16);
    }
    __syncthreads();

    const int lane = threadIdx.x & 63, ww = threadIdx.x >> 6;
    const int quad = lane >> 4, l16 = lane & 15;
    const int nodeBase = blockIdx.x * 64 + ww * 16;
    int arow = nodeBase + l16;
    if (arow >= N) arow = N - 1;
    const short* xp = (const short*)xv + (size_t)arow * C1 + quad * 8;
    short8 afr[4];
#pragma unroll
    for (int kk = 0; kk < 4; ++kk) afr[kk] = *(const short8*)(xp + kk * 32);

    const __hip_bfloat16* asrc = (const __hip_bfloat16*)a_srcv;
    const __hip_bfloat16* adst = (const __hip_bfloat16*)a_dstv;
    float sacc[4], dacc[4];
#pragma unroll
    for (int ct = 0; ct < 8; ++ct) {
        floatx4 acc = {0.f, 0.f, 0.f, 0.f};
        const int col = ct * 16 + l16;
        const unsigned short* bbase = &Bs[col * 136 + quad * 8];
#pragma unroll
        for (int kk = 0; kk < 4; ++kk) {
            short8 bfr = *(const short8*)(bbase + kk * 32);
            acc = __builtin_amdgcn_mfma_f32_16x16x32_bf16(afr[kk], bfr, acc, 0, 0, 0);
        }
#pragma unroll
        for (int reg = 0; reg < 4; ++reg) {
            int node = nodeBase + quad * 4 + reg;
            if (node < N) h1b[(size_t)node * C1 + col] = __float2bfloat16(acc[reg]);
        }
        float av = (float)asrc[col];
        float dv = (float)adst[col];
        if ((ct & 1) == 0) {
#pragma unroll
            for (int r = 0; r < 4; ++r) { sacc[r] = 0.f; dacc[r] = 0.f; }
        }
#pragma unroll
        for (int reg = 0; reg < 4; ++reg) {
            float ts = acc[reg] * av;
            float td = acc[reg] * dv;
#pragma unroll
            for (int o = 1; o < 16; o <<= 1) {
                ts += __shfl_xor(ts, o, 64);
                td += __shfl_xor(td, o, 64);
            }
            sacc[reg] += ts;
            dacc[reg] += td;
        }
        if ((ct & 1) == 1 && l16 == 0) {
            int h = ct >> 1;
#pragma unroll
            for (int reg = 0; reg < 4; ++reg) {
                int node = nodeBase + quad * 4 + reg;
                if (node < N) {
                    as1[node * 4 + h] = sacc[reg];
                    ad1[node * 4 + h] = dacc[reg];
                }
            }
        }
    }
}

// ---------------- Layer 1 GEMM vector fallback (fp32 inputs) ----------------
__global__ __launch_bounds__(128)
void gemm1_vec_kernel(const float* __restrict__ x, const float* __restrict__ W1,
                      const float* __restrict__ a_src, const float* __restrict__ a_dst,
                      float* __restrict__ h1, float* __restrict__ as1,
                      float* __restrict__ ad1, int N, const int* __restrict__ dflag) {
    if (*dflag != 0) return;
    __shared__ float xs[8][C1];
    const int t = threadIdx.x;
    const int n0 = blockIdx.x * 8;
#pragma unroll
    for (int j = 0; j < 8; ++j) {
        int n = n0 + j;
        xs[j][t] = (n < N) ? x[(size_t)n * C1 + t] : 0.f;
    }
    __syncthreads();
    float acc[8] = {0.f,0.f,0.f,0.f,0.f,0.f,0.f,0.f};
    for (int k = 0; k < 128; ++k) {
        float wv = W1[k * C1 + t];
#pragma unroll
        for (int j = 0; j < 8; ++j) acc[j] += xs[j][k] * wv;
    }
    const float asv = a_src[t];
    const float adv = a_dst[t];
    const int head = t >> 5;
#pragma unroll
    for (int j = 0; j < 8; ++j) {
        int n = n0 + j;
        if (n < N) h1[(size_t)n * C1 + t] = acc[j];
        float ps = acc[j] * asv;
        float pd = acc[j] * adv;
#pragma unroll
        for (int o = 16; o >= 1; o >>= 1) {
            ps += __shfl_xor(ps, o, 32);
            pd += __shfl_xor(pd, o, 32);
        }
        if ((t & 31) == 0 && n < N) {
            as1[n * 4 + head] = ps;
            ad1[n * 4 + head] = pd;
        }
    }
}

// ---------------- Layer 1 CSR gather v3: wave/dst, dword gathers ----------------
template <bool BF>
__device__ __forceinline__ void msg1_body_v3(const int* __restrict__ offs,
                                             const int* __restrict__ csrc,
                                             const void* __restrict__ h1,
                                             const float* __restrict__ as1,
                                             const float* __restrict__ ad1,
                                             const void* __restrict__ b1,
                                             void* __restrict__ out1, int d) {
    const int lane = threadIdx.x & 63;
    const int beg = offs[d], end = offs[d + 1];
    const int k8 = lane & 7;
    const int whead = (lane >> 3) & 3;     // weight-lane head (lanes 0..31)
    const int myHead = lane >> 4;          // consumer head for ch pair (2*lane)
    const float wadh = ad1[d * 4 + whead];
    float accx = 0.f, accy = 0.f, sumw = 0.f;
    for (int jj = beg; jj < end; jj += 8) {
        int idx = jj + k8;
        if (idx >= end) idx = end - 1;
        const int myS = csrc[idx];
        int s[8];
#pragma unroll
        for (int k = 0; k < 8; ++k) s[k] = __shfl(myS, k, 64);
        float vx[8], vy[8];
        if (BF) {
            const unsigned* h1u = (const unsigned*)h1;
            unsigned rv[8];
#pragma unroll
            for (int k = 0; k < 8; ++k) rv[k] = h1u[(size_t)s[k] * 64 + lane];
#pragma unroll
            for (int k = 0; k < 8; ++k) {
                vx[k] = __uint_as_float(rv[k] << 16);
                vy[k] = __uint_as_float(rv[k] & 0xFFFF0000u);
            }
        } else {
            const float2* h1f = (const float2*)h1;
            float2 rv[8];
#pragma unroll
            for (int k = 0; k < 8; ++k) rv[k] = h1f[(size_t)s[k] * 64 + lane];
#pragma unroll
            for (int k = 0; k < 8; ++k) { vx[k] = rv[k].x; vy[k] = rv[k].y; }
        }
        float w = 0.f;
        if (lane < 32 && jj + k8 < end) {
            float a = as1[myS * 4 + whead];
            w = __expf(lrelu(a + wadh));
        }
#pragma unroll
        for (int k = 0; k < 8; ++k) {
            float wk = __shfl(w, myHead * 8 + k, 64);
            sumw += wk;
            accx += wk * vx[k];
            accy += wk * vy[k];
        }
    }
    float inv = (sumw > 0.f) ? 1.f / sumw : 0.f;
    float rx = accx * inv + ldin(b1, 2 * lane, BF);
    float ry = accy * inv + ldin(b1, 2 * lane + 1, BF);
    rx = rx > 0.f ? rx : expm1f(rx);
    ry = ry > 0.f ? ry : expm1f(ry);
    if (BF) {
        __hip_bfloat162 p;
        p.x = __float2bfloat16(rx);
        p.y = __float2bfloat16(ry);
        ((__hip_bfloat162*)out1)[(size_t)d * 64 + lane] = p;
    } else {
        float2 p; p.x = rx; p.y = ry;
        ((float2*)out1)[(size_t)d * 64 + lane] = p;
    }
}

__global__ __launch_bounds__(256)
void msg1_csr_kernel(const int* __restrict__ offs, const int* __restrict__ csrc,
                     const void* __restrict__ h1, const float* __restrict__ as1,
                     const float* __restrict__ ad1, const void* __restrict__ b1,
                     void* __restrict__ out1, int N, const int* __restrict__ dflag) {
    const bool bf = (*dflag != 0);
    const int d = blockIdx.x * 4 + (threadIdx.x >> 6);
    if (d >= N) return;
    if (bf) msg1_body_v3<true>(offs, csrc, h1, as1, ad1, b1, out1, d);
    else    msg1_body_v3<false>(offs, csrc, h1, as1, ad1, b1, out1, d);
}

// ---------------- Layer 2 GEMM via MFMA (bf16 mode) ----------------
__global__ __launch_bounds__(256)
void gemm2_mfma_kernel(const __hip_bfloat16* __restrict__ h2b,
                       const void* __restrict__ W2v,
                       const void* __restrict__ a_srcv, const void* __restrict__ a_dstv,
                       __hip_bfloat16* __restrict__ g2b,
                       float* __restrict__ as2, float* __restrict__ ad2,
                       int N, const int* __restrict__ dflag) {
    if (*dflag == 0) return;
    __shared__ __align__(16) unsigned short Bs[64 * 136];
    const unsigned short* Wg = (const unsigned short*)W2v;
    for (int i = threadIdx.x; i < 64 * 64; i += 256) {
        int col = i & 63;
        int k = (i >> 6) * 2;
        unsigned w0 = Wg[k * 64 + col];
        unsigned w1 = Wg[(k + 1) * 64 + col];
        *(unsigned*)&Bs[col * 136 + k] = w0 | (w1 << 16);
    }
    __syncthreads();

    const int lane = threadIdx.x & 63, ww = threadIdx.x >> 6;
    const int quad = lane >> 4, l16 = lane & 15;
    const int nodeBase = blockIdx.x * 64 + ww * 16;
    int arow = nodeBase + l16;
    if (arow >= N) arow = N - 1;
    const short* xp = (const short*)h2b + (size_t)arow * C1 + quad * 8;
    short8 afr[4];
#pragma unroll
    for (int kk = 0; kk < 4; ++kk) afr[kk] = *(const short8*)(xp + kk * 32);

    const __hip_bfloat16* asrc = (const __hip_bfloat16*)a_srcv;
    const __hip_bfloat16* adst = (const __hip_bfloat16*)a_dstv;
    float sacc[4] = {0.f,0.f,0.f,0.f}, dacc[4] = {0.f,0.f,0.f,0.f};
#pragma unroll
    for (int ct = 0; ct < 4; ++ct) {
        floatx4 acc = {0.f, 0.f, 0.f, 0.f};
        const int col = ct * 16 + l16;
        const unsigned short* bbase = &Bs[col * 136 + quad * 8];
#pragma unroll
        for (int kk = 0; kk < 4; ++kk) {
            short8 bfr = *(const short8*)(bbase + kk * 32);
            acc = __builtin_amdgcn_mfma_f32_16x16x32_bf16(afr[kk], bfr, acc, 0, 0, 0);
        }
#pragma unroll
        for (int reg = 0; reg < 4; ++reg) {
            int node = nodeBase + quad * 4 + reg;
            if (node < N) g2b[(size_t)node * C2 + col] = __float2bfloat16(acc[reg]);
        }
        float av = (float)asrc[col];
        float dv = (float)adst[col];
#pragma unroll
        for (int reg = 0; reg < 4; ++reg) {
            float ts = acc[reg] * av;
            float td = acc[reg] * dv;
#pragma unroll
            for (int o = 1; o < 16; o <<= 1) {
                ts += __shfl_xor(ts, o, 64);
                td += __shfl_xor(td, o, 64);
            }
            sacc[reg] += ts;
            dacc[reg] += td;
        }
    }
    if (l16 == 0) {
#pragma unroll
        for (int reg = 0; reg < 4; ++reg) {
            int node = nodeBase + quad * 4 + reg;
            if (node < N) { as2[node] = sacc[reg]; ad2[node] = dacc[reg]; }
        }
    }
}

// ---------------- Layer 2 GEMM vector fallback (fp32 mode) ----------------
__global__ __launch_bounds__(64)
void gemm2_vec_kernel(const float* __restrict__ h2, const float* __restrict__ W2,
                      const float* __restrict__ a_src, const float* __restrict__ a_dst,
                      float* __restrict__ g2, float* __restrict__ as2,
                      float* __restrict__ ad2, int N, const int* __restrict__ dflag) {
    if (*dflag != 0) return;
    __shared__ __align__(16) float xs[8][C1];
    const int t = threadIdx.x;
    const int n0 = blockIdx.x * 8;
#pragma unroll
    for (int j = 0; j < 8; ++j) {
        int n = n0 + j;
        if (n < N) {
            float2 v = *(const float2*)&h2[(size_t)n * C1 + t * 2];
            xs[j][t * 2] = v.x; xs[j][t * 2 + 1] = v.y;
        } else { xs[j][t * 2] = 0.f; xs[j][t * 2 + 1] = 0.f; }
    }
    __syncthreads();
    float acc[8] = {0.f,0.f,0.f,0.f,0.f,0.f,0.f,0.f};
    for (int k = 0; k < 128; k += 4) {
        float w0 = W2[(k + 0) * C2 + t], w1 = W2[(k + 1) * C2 + t];
        float w2 = W2[(k + 2) * C2 + t], w3 = W2[(k + 3) * C2 + t];
#pragma unroll
        for (int j = 0; j < 8; ++j) {
            float4 xv = *(const float4*)&xs[j][k];
            acc[j] += xv.x * w0 + xv.y * w1 + xv.z * w2 + xv.w * w3;
        }
    }
    const float asv = a_src[t];
    const float adv = a_dst[t];
#pragma unroll
    for (int j = 0; j < 8; ++j) {
        int n = n0 + j;
        if (n < N) g2[(size_t)n * C2 + t] = acc[j];
        float ps = acc[j] * asv;
        float pd = acc[j] * adv;
#pragma unroll
        for (int o = 32; o >= 1; o >>= 1) {
            ps += __shfl_xor(ps, o, 64);
            pd += __shfl_xor(pd, o, 64);
        }
        if (t == 0 && n < N) { as2[n] = ps; ad2[n] = pd; }
    }
}

// ---------------- Layer 2 CSR gather v3: wave/dst, dual-edge halves ----------------
template <bool BF>
__device__ __forceinline__ void msg2_body_v3(const int* __restrict__ offs,
                                             const int* __restrict__ csrc,
                                             const void* __restrict__ g2,
                                             const float* __restrict__ as2,
                                             const float* __restrict__ ad2,
                                             const void* __restrict__ b2,
                                             void* __restrict__ y, int d) {
    const int lane = threadIdx.x & 63;
    const int half = lane >> 5;
    const int l32 = lane & 31;
    const int k16 = lane & 15;
    const int beg = offs[d], end = offs[d + 1];
    const float add = ad2[d];
    float accx = 0.f, accy = 0.f, sumw = 0.f;
    for (int jj = beg; jj < end; jj += 16) {
        int idx = jj + k16;
        if (idx >= end) idx = end - 1;
        const int myS = csrc[idx];
        float w = 0.f;
        if (lane < 16 && jj + k16 < end)
            w = __expf(lrelu(as2[myS] + add));
        int s[8];
#pragma unroll
        for (int k = 0; k < 8; ++k) s[k] = __shfl(myS, 2 * k + half, 64);
        float vx[8], vy[8];
        if (BF) {
            const unsigned* gu = (const unsigned*)g2;
            unsigned rv[8];
#pragma unroll
            for (int k = 0; k < 8; ++k) rv[k] = gu[(size_t)s[k] * 32 + l32];
#pragma unroll
            for (int k = 0; k < 8; ++k) {
                vx[k] = __uint_as_float(rv[k] << 16);
                vy[k] = __uint_as_float(rv[k] & 0xFFFF0000u);
            }
        } else {
            const float2* gf = (const float2*)g2;
            float2 rv[8];
#pragma unroll
            for (int k = 0; k < 8; ++k) rv[k] = gf[(size_t)s[k] * 32 + l32];
#pragma unroll
            for (int k = 0; k < 8; ++k) { vx[k] = rv[k].x; vy[k] = rv[k].y; }
        }
#pragma unroll
        for (int k = 0; k < 8; ++k) {
            float wk = __shfl(w, 2 * k + half, 64);
            sumw += wk;
            accx += wk * vx[k];
            accy += wk * vy[k];
        }
    }
    accx += __shfl_xor(accx, 32, 64);
    accy += __shfl_xor(accy, 32, 64);
    sumw += __shfl_xor(sumw, 32, 64);
    if (half == 0) {
        float inv = (sumw > 0.f) ? 1.f / sumw : 0.f;
        float rx = accx * inv + ldin(b2, 2 * l32, BF);
        float ry = accy * inv + ldin(b2, 2 * l32 + 1, BF);
        if (BF) {
            __hip_bfloat162 p;
            p.x = __float2bfloat16(rx);
            p.y = __float2bfloat16(ry);
            ((__hip_bfloat162*)y)[(size_t)d * 32 + l32] = p;
        } else {
            float2 p; p.x = rx; p.y = ry;
            ((float2*)y)[(size_t)d * 32 + l32] = p;
        }
    }
}

__global__ __launch_bounds__(256)
void msg2_csr_kernel(const int* __restrict__ offs, const int* __restrict__ csrc,
                     const void* __restrict__ g2, const float* __restrict__ as2,
                     const float* __restrict__ ad2, const void* __restrict__ b2,
                     void* __restrict__ y, int N, const int* __restrict__ dflag) {
    const bool bf = (*dflag != 0);
    const int d = blockIdx.x * 4 + (threadIdx.x >> 6);
    if (d >= N) return;
    if (bf) msg2_body_v3<true>(offs, csrc, g2, as2, ad2, b2, y, d);
    else    msg2_body_v3<false>(offs, csrc, g2, as2, ad2, b2, y, d);
}

extern "C" void kernel_launch(void* const* d_in, const int* in_sizes, int n_in,
                              void* d_out, int out_size, void* d_ws, size_t ws_size,
                              hipStream_t stream) {
    const void* x    = d_in[0];
    const int*  ei   = (const int*)d_in[1];
    const void* W1   = d_in[2];
    const void* a_s1 = d_in[3];
    const void* a_d1 = d_in[4];
    const void* b1   = d_in[5];
    const void* W2   = d_in[6];
    const void* a_s2 = d_in[7];
    const void* a_d2 = d_in[8];
    const void* b2   = d_in[9];

    const int N = in_sizes[0] / C1;
    const int E = in_sizes[1] / 2;

    auto align16 = [](size_t v) { return (v + 15) & ~(size_t)15; };
    const size_t RF   = 16;
    const size_t ROFF = align16((size_t)(N + 1) * 4);
    const size_t RCUR = align16((size_t)N * 4);
    const size_t RBS  = 256;
    const size_t RSRC = align16((size_t)E * 4);
    const size_t R1   = align16((size_t)N * C1 * 4);   // h1/g2 (fp32 worst case)
    const size_t R2   = align16((size_t)N * 8 * 4);    // as1+ad1 / as2+ad2

    char* base = (char*)d_ws;
    int*  dflag  = (int*)base;
    int*  offs   = (int*)(base + RF);
    int*  cursor = (int*)(base + RF + ROFF);
    int*  bsum   = (int*)(base + RF + ROFF + RCUR);
    int*  csrc   = (int*)(base + RF + ROFF + RCUR + RBS);
    char* R1p = base + RF + ROFF + RCUR + RBS + RSRC;
    char* R2p = R1p + R1;
    char* R4p = R2p + R2;
    (void)ws_size;

    void*  h1  = (void*)R1p;
    void*  g2  = (void*)R1p;
    float* as1 = (float*)R2p;
    float* ad1 = as1 + (size_t)N * 4;
    float* as2 = (float*)R2p;
    float* ad2 = as2 + N;
    void*  out1 = (void*)R4p;

    const int nbScan = (N + 1023) / 1024;
    const int nbTile = (N + 63) / 64;
    const int nbWave4 = (N + 3) / 4;

    detect_kernel<<<1, 256, 0, stream>>>((const unsigned*)x, 2048, dflag);
    hipMemsetAsync(cursor, 0, (size_t)N * 4, stream);
    count_kernel<<<1024, 256, 0, stream>>>(ei, cursor, N, E);
    scanA_kernel<<<nbScan, 1024, 0, stream>>>(cursor, offs, bsum, N);
    scanB_kernel<<<1, 64, 0, stream>>>(bsum, &offs[N], nbScan);
    scanC_kernel<<<nbScan, 1024, 0, stream>>>(offs, cursor, bsum, N);
    fill_kernel<<<1024, 256, 0, stream>>>(ei, cursor, csrc, N, E);

    gemm1_mfma_kernel<<<nbTile, 256, 0, stream>>>(x, W1, a_s1, a_d1,
        (__hip_bfloat16*)h1, as1, ad1, N, dflag);
    gemm1_vec_kernel<<<(N + 7) / 8, 128, 0, stream>>>((const float*)x, (const float*)W1,
        (const float*)a_s1, (const float*)a_d1, (float*)h1, as1, ad1, N, dflag);

    msg1_csr_kernel<<<nbWave4, 256, 0, stream>>>(offs, csrc, h1, as1, ad1, b1, out1, N, dflag);

    gemm2_mfma_kernel<<<nbTile, 256, 0, stream>>>((const __hip_bfloat16*)out1, W2,
        a_s2, a_d2, (__hip_bfloat16*)g2, as2, ad2, N, dflag);
    gemm2_vec_kernel<<<(N + 7) / 8, 64, 0, stream>>>((const float*)out1, (const float*)W2,
        (const float*)a_s2, (const float*)a_d2, (float*)g2, as2, ad2, N, dflag);

    msg2_csr_kernel<<<nbWave4, 256, 0, stream>>>(offs, csrc, g2, as2, ad2, b2, d_out, N, dflag);
}

// Round 11
// 322.798 us; speedup vs baseline: 3.1949x; 1.1559x over previous
//
#include <hip/hip_runtime.h>
#include <hip/hip_bf16.h>

#define C1 128   // heads1(4) * hid(32)
#define C2 64    // out channels layer 2

typedef __attribute__((ext_vector_type(8))) short short8;
typedef __attribute__((ext_vector_type(4))) float floatx4;

__device__ __forceinline__ float lrelu(float v) { return v > 0.f ? v : 0.2f * v; }

// fp32 -> bf16 bits with round-to-nearest-even
__device__ __forceinline__ unsigned short f2bf(float f) {
    unsigned u = __float_as_uint(f);
    u += 0x7FFFu + ((u >> 16) & 1u);
    return (unsigned short)(u >> 16);
}

// ---------------- CSR build (proven rounds 3-8) ----------------
__global__ __launch_bounds__(256)
void count_kernel(const int* __restrict__ ei, int* __restrict__ deg, int N, int E) {
    for (int e = blockIdx.x * blockDim.x + threadIdx.x; e < E;
         e += gridDim.x * blockDim.x) {
        int d = ei[E + e];
        if ((unsigned)d < (unsigned)N) atomicAdd(&deg[d], 1);
    }
}

__global__ __launch_bounds__(1024)
void scanA_kernel(const int* __restrict__ deg, int* __restrict__ offs,
                  int* __restrict__ bsum, int N) {
    __shared__ int wsum[16];
    const int i = blockIdx.x * 1024 + threadIdx.x;
    const int lane = threadIdx.x & 63, wid = threadIdx.x >> 6;
    int v = (i < N) ? deg[i] : 0;
    int x = v;
#pragma unroll
    for (int o = 1; o < 64; o <<= 1) {
        int y = __shfl_up(x, o, 64);
        if (lane >= o) x += y;
    }
    if (lane == 63) wsum[wid] = x;
    __syncthreads();
    if (wid == 0 && lane < 16) {
        int s = wsum[lane];
#pragma unroll
        for (int o = 1; o < 16; o <<= 1) {
            int y = __shfl_up(s, o, 16);
            if (lane >= o) s += y;
        }
        wsum[lane] = s;
    }
    __syncthreads();
    int pre = (wid > 0) ? wsum[wid - 1] : 0;
    int incl = x + pre;
    if (i < N) offs[i] = incl - v;
    if (threadIdx.x == 1023) bsum[blockIdx.x] = incl;
}

__global__ __launch_bounds__(64)
void scanB_kernel(int* __restrict__ bsum, int* __restrict__ offs_end, int nb) {
    const int lane = threadIdx.x;
    if (nb <= 64) {
        int v = (lane < nb) ? bsum[lane] : 0;
        int x = v;
#pragma unroll
        for (int o = 1; o < 64; o <<= 1) {
            int y = __shfl_up(x, o, 64);
            if (lane >= o) x += y;
        }
        if (lane < nb) bsum[lane] = x - v;
        int tot = __shfl(x, 63, 64);
        if (lane == 0) *offs_end = tot;
    } else if (lane == 0) {
        int run = 0;
        for (int b = 0; b < nb; ++b) { int t = bsum[b]; bsum[b] = run; run += t; }
        *offs_end = run;
    }
}

__global__ __launch_bounds__(1024)
void scanC_kernel(int* __restrict__ offs, int* __restrict__ cursor,
                  const int* __restrict__ bsum, int N) {
    const int i = blockIdx.x * 1024 + threadIdx.x;
    if (i < N) {
        int o = offs[i] + bsum[blockIdx.x];
        offs[i] = o;
        cursor[i] = o;
    }
}

__global__ __launch_bounds__(256)
void fill_kernel(const int* __restrict__ ei, int* __restrict__ cursor,
                 int* __restrict__ csrc, int N, int E) {
    for (int e = blockIdx.x * blockDim.x + threadIdx.x; e < E;
         e += gridDim.x * blockDim.x) {
        int s = ei[e], d = ei[E + e];
        if ((unsigned)s >= (unsigned)N || (unsigned)d >= (unsigned)N) continue;
        int pos = atomicAdd(&cursor[d], 1);
        csrc[pos] = s;
    }
}

// ---------------- Layer 1 GEMM: fp32 in, MFMA bf16 core, fp32 out ----------------
// x[N,128]f32 @ W1[128,128]f32 -> h1 f32; fused alpha dots (f32).
__global__ __launch_bounds__(256)
void gemm1_mfma_kernel(const float* __restrict__ x, const float* __restrict__ W1,
                       const float* __restrict__ asrc, const float* __restrict__ adst,
                       float* __restrict__ h1, float* __restrict__ as1,
                       float* __restrict__ ad1, int N) {
    // W1 transposed into LDS as bf16: Bs[col][k], stride 136 (2-way banks: free)
    __shared__ __align__(16) unsigned short Bs[128 * 136];
    for (int i = threadIdx.x; i < 128 * 64; i += 256) {
        int col = i & 127;
        int k = (i >> 7) * 2;
        unsigned w0 = f2bf(W1[k * 128 + col]);
        unsigned w1 = f2bf(W1[(k + 1) * 128 + col]);
        *(unsigned*)&Bs[col * 136 + k] = w0 | (w1 << 16);
    }
    __syncthreads();

    const int lane = threadIdx.x & 63, ww = threadIdx.x >> 6;
    const int quad = lane >> 4, l16 = lane & 15;
    const int nodeBase = blockIdx.x * 64 + ww * 16;
    int arow = nodeBase + l16;
    if (arow >= N) arow = N - 1;                       // clamp loads; stores guarded
    const float* xp = x + (size_t)arow * C1 + quad * 8;
    short8 afr[4];
#pragma unroll
    for (int kk = 0; kk < 4; ++kk) {
        float4 a0 = *(const float4*)(xp + kk * 32);
        float4 a1 = *(const float4*)(xp + kk * 32 + 4);
        short8 fr;
        fr[0] = (short)f2bf(a0.x); fr[1] = (short)f2bf(a0.y);
        fr[2] = (short)f2bf(a0.z); fr[3] = (short)f2bf(a0.w);
        fr[4] = (short)f2bf(a1.x); fr[5] = (short)f2bf(a1.y);
        fr[6] = (short)f2bf(a1.z); fr[7] = (short)f2bf(a1.w);
        afr[kk] = fr;
    }

    float sacc[4], dacc[4];
#pragma unroll
    for (int ct = 0; ct < 8; ++ct) {
        floatx4 acc = {0.f, 0.f, 0.f, 0.f};
        const int col = ct * 16 + l16;
        const unsigned short* bbase = &Bs[col * 136 + quad * 8];
#pragma unroll
        for (int kk = 0; kk < 4; ++kk) {
            short8 bfr = *(const short8*)(bbase + kk * 32);
            acc = __builtin_amdgcn_mfma_f32_16x16x32_bf16(afr[kk], bfr, acc, 0, 0, 0);
        }
        // C/D layout: col=lane&15, row=quad*4+reg  [m89/m91 verified]
#pragma unroll
        for (int reg = 0; reg < 4; ++reg) {
            int node = nodeBase + quad * 4 + reg;
            if (node < N) h1[(size_t)node * C1 + col] = acc[reg];
        }
        float av = asrc[col];
        float dv = adst[col];
        if ((ct & 1) == 0) {
#pragma unroll
            for (int r = 0; r < 4; ++r) { sacc[r] = 0.f; dacc[r] = 0.f; }
        }
#pragma unroll
        for (int reg = 0; reg < 4; ++reg) {
            float ts = acc[reg] * av;
            float td = acc[reg] * dv;
#pragma unroll
            for (int o = 1; o < 16; o <<= 1) {
                ts += __shfl_xor(ts, o, 64);
                td += __shfl_xor(td, o, 64);
            }
            sacc[reg] += ts;
            dacc[reg] += td;
        }
        if ((ct & 1) == 1 && l16 == 0) {
            int h = ct >> 1;
#pragma unroll
            for (int reg = 0; reg < 4; ++reg) {
                int node = nodeBase + quad * 4 + reg;
                if (node < N) {
                    as1[node * 4 + h] = sacc[reg];
                    ad1[node * 4 + h] = dacc[reg];
                }
            }
        }
    }
}

// ---------------- Layer 1 CSR gather (round-8 executed fp32 path, verbatim) ----------------
__global__ __launch_bounds__(256)
void msg1_csr_kernel(const int* __restrict__ offs, const int* __restrict__ csrc,
                     const float2* __restrict__ h1f, const float* __restrict__ as1,
                     const float* __restrict__ ad1, const float* __restrict__ b1,
                     float2* __restrict__ out1, int N) {
    const int d = blockIdx.x * 4 + (threadIdx.x >> 6);
    if (d >= N) return;
    const int lane = threadIdx.x & 63;
    const int beg = offs[d], end = offs[d + 1];
    const int k8 = lane & 7;
    const int whead = (lane >> 3) & 3;     // weight-lane head (lanes 0..31)
    const int myHead = lane >> 4;          // consumer head for ch pair (2*lane)
    const float wadh = ad1[d * 4 + whead];
    float accx = 0.f, accy = 0.f, sumw = 0.f;
    for (int jj = beg; jj < end; jj += 8) {
        int idx = jj + k8;
        if (idx >= end) idx = end - 1;
        const int myS = csrc[idx];
        int s[8];
#pragma unroll
        for (int k = 0; k < 8; ++k) s[k] = __shfl(myS, k, 64);
        float2 rv[8];
#pragma unroll
        for (int k = 0; k < 8; ++k) rv[k] = h1f[(size_t)s[k] * 64 + lane];
        float w = 0.f;
        if (lane < 32 && jj + k8 < end) {
            float a = as1[myS * 4 + whead];
            w = __expf(lrelu(a + wadh));
        }
#pragma unroll
        for (int k = 0; k < 8; ++k) {
            float wk = __shfl(w, myHead * 8 + k, 64);
            sumw += wk;
            accx += wk * rv[k].x;
            accy += wk * rv[k].y;
        }
    }
    float inv = (sumw > 0.f) ? 1.f / sumw : 0.f;
    float rx = accx * inv + b1[2 * lane];
    float ry = accy * inv + b1[2 * lane + 1];
    rx = rx > 0.f ? rx : expm1f(rx);
    ry = ry > 0.f ? ry : expm1f(ry);
    float2 p; p.x = rx; p.y = ry;
    out1[(size_t)d * 64 + lane] = p;
}

// ---------------- Layer 2 GEMM: fp32 in, MFMA bf16 core, fp32 out ----------------
__global__ __launch_bounds__(256)
void gemm2_mfma_kernel(const float* __restrict__ h2, const float* __restrict__ W2,
                       const float* __restrict__ asrc, const float* __restrict__ adst,
                       float* __restrict__ g2, float* __restrict__ as2,
                       float* __restrict__ ad2, int N) {
    __shared__ __align__(16) unsigned short Bs[64 * 136];
    for (int i = threadIdx.x; i < 64 * 64; i += 256) {
        int col = i & 63;
        int k = (i >> 6) * 2;
        unsigned w0 = f2bf(W2[k * 64 + col]);
        unsigned w1 = f2bf(W2[(k + 1) * 64 + col]);
        *(unsigned*)&Bs[col * 136 + k] = w0 | (w1 << 16);
    }
    __syncthreads();

    const int lane = threadIdx.x & 63, ww = threadIdx.x >> 6;
    const int quad = lane >> 4, l16 = lane & 15;
    const int nodeBase = blockIdx.x * 64 + ww * 16;
    int arow = nodeBase + l16;
    if (arow >= N) arow = N - 1;
    const float* xp = h2 + (size_t)arow * C1 + quad * 8;
    short8 afr[4];
#pragma unroll
    for (int kk = 0; kk < 4; ++kk) {
        float4 a0 = *(const float4*)(xp + kk * 32);
        float4 a1 = *(const float4*)(xp + kk * 32 + 4);
        short8 fr;
        fr[0] = (short)f2bf(a0.x); fr[1] = (short)f2bf(a0.y);
        fr[2] = (short)f2bf(a0.z); fr[3] = (short)f2bf(a0.w);
        fr[4] = (short)f2bf(a1.x); fr[5] = (short)f2bf(a1.y);
        fr[6] = (short)f2bf(a1.z); fr[7] = (short)f2bf(a1.w);
        afr[kk] = fr;
    }

    float sacc[4] = {0.f,0.f,0.f,0.f}, dacc[4] = {0.f,0.f,0.f,0.f};
#pragma unroll
    for (int ct = 0; ct < 4; ++ct) {
        floatx4 acc = {0.f, 0.f, 0.f, 0.f};
        const int col = ct * 16 + l16;
        const unsigned short* bbase = &Bs[col * 136 + quad * 8];
#pragma unroll
        for (int kk = 0; kk < 4; ++kk) {
            short8 bfr = *(const short8*)(bbase + kk * 32);
            acc = __builtin_amdgcn_mfma_f32_16x16x32_bf16(afr[kk], bfr, acc, 0, 0, 0);
        }
#pragma unroll
        for (int reg = 0; reg < 4; ++reg) {
            int node = nodeBase + quad * 4 + reg;
            if (node < N) g2[(size_t)node * C2 + col] = acc[reg];
        }
        float av = asrc[col];
        float dv = adst[col];
#pragma unroll
        for (int reg = 0; reg < 4; ++reg) {
            float ts = acc[reg] * av;
            float td = acc[reg] * dv;
#pragma unroll
            for (int o = 1; o < 16; o <<= 1) {
                ts += __shfl_xor(ts, o, 64);
                td += __shfl_xor(td, o, 64);
            }
            sacc[reg] += ts;
            dacc[reg] += td;
        }
    }
    if (l16 == 0) {
#pragma unroll
        for (int reg = 0; reg < 4; ++reg) {
            int node = nodeBase + quad * 4 + reg;
            if (node < N) { as2[node] = sacc[reg]; ad2[node] = dacc[reg]; }
        }
    }
}

// ---------------- Layer 2 CSR gather (round-8 executed fp32 path, verbatim) ----------------
__global__ __launch_bounds__(256)
void msg2_csr_kernel(const int* __restrict__ offs, const int* __restrict__ csrc,
                     const float2* __restrict__ g2f, const float* __restrict__ as2,
                     const float* __restrict__ ad2, const float* __restrict__ b2,
                     float2* __restrict__ y, int N) {
    const int d = blockIdx.x * 4 + (threadIdx.x >> 6);
    if (d >= N) return;
    const int lane = threadIdx.x & 63;
    const int half = lane >> 5;
    const int l32 = lane & 31;
    const int k16 = lane & 15;
    const int beg = offs[d], end = offs[d + 1];
    const float add = ad2[d];
    float accx = 0.f, accy = 0.f, sumw = 0.f;
    for (int jj = beg; jj < end; jj += 16) {
        int idx = jj + k16;
        if (idx >= end) idx = end - 1;
        const int myS = csrc[idx];
        float w = 0.f;
        if (lane < 16 && jj + k16 < end)
            w = __expf(lrelu(as2[myS] + add));
        int s[8];
#pragma unroll
        for (int k = 0; k < 8; ++k) s[k] = __shfl(myS, 2 * k + half, 64);
        float2 rv[8];
#pragma unroll
        for (int k = 0; k < 8; ++k) rv[k] = g2f[(size_t)s[k] * 32 + l32];
#pragma unroll
        for (int k = 0; k < 8; ++k) {
            float wk = __shfl(w, 2 * k + half, 64);
            sumw += wk;
            accx += wk * rv[k].x;
            accy += wk * rv[k].y;
        }
    }
    accx += __shfl_xor(accx, 32, 64);
    accy += __shfl_xor(accy, 32, 64);
    sumw += __shfl_xor(sumw, 32, 64);
    if (half == 0) {
        float inv = (sumw > 0.f) ? 1.f / sumw : 0.f;
        float2 p;
        p.x = accx * inv + b2[2 * l32];
        p.y = accy * inv + b2[2 * l32 + 1];
        y[(size_t)d * 32 + l32] = p;
    }
}

extern "C" void kernel_launch(void* const* d_in, const int* in_sizes, int n_in,
                              void* d_out, int out_size, void* d_ws, size_t ws_size,
                              hipStream_t stream) {
    const float* x    = (const float*)d_in[0];
    const int*   ei   = (const int*)d_in[1];
    const float* W1   = (const float*)d_in[2];
    const float* a_s1 = (const float*)d_in[3];
    const float* a_d1 = (const float*)d_in[4];
    const float* b1   = (const float*)d_in[5];
    const float* W2   = (const float*)d_in[6];
    const float* a_s2 = (const float*)d_in[7];
    const float* a_d2 = (const float*)d_in[8];
    const float* b2   = (const float*)d_in[9];

    const int N = in_sizes[0] / C1;
    const int E = in_sizes[1] / 2;

    // Layout identical to rounds 3-8 (proven footprint).
    auto align16 = [](size_t v) { return (v + 15) & ~(size_t)15; };
    const size_t RF   = 16;
    const size_t ROFF = align16((size_t)(N + 1) * 4);
    const size_t RCUR = align16((size_t)N * 4);
    const size_t RBS  = 256;
    const size_t RSRC = align16((size_t)E * 4);
    const size_t R1   = align16((size_t)N * C1 * 4);   // h1 / g2 (fp32)
    const size_t R2   = align16((size_t)N * 8 * 4);    // as1+ad1 / as2+ad2

    char* base = (char*)d_ws;
    int*  offs   = (int*)(base + RF);
    int*  cursor = (int*)(base + RF + ROFF);
    int*  bsum   = (int*)(base + RF + ROFF + RCUR);
    int*  csrc   = (int*)(base + RF + ROFF + RCUR + RBS);
    char* R1p = base + RF + ROFF + RCUR + RBS + RSRC;
    char* R2p = R1p + R1;
    char* R4p = R2p + R2;
    (void)ws_size;

    float* h1  = (float*)R1p;
    float* g2  = (float*)R1p;                 // h1 dead after msg1
    float* as1 = (float*)R2p;
    float* ad1 = as1 + (size_t)N * 4;
    float* as2 = (float*)R2p;                 // as1/ad1 dead after msg1
    float* ad2 = as2 + N;
    float* out1 = (float*)R4p;                // fp32 N*C1

    const int nbScan = (N + 1023) / 1024;
    const int nbTile = (N + 63) / 64;
    const int nbWave4 = (N + 3) / 4;

    hipMemsetAsync(cursor, 0, (size_t)N * 4, stream);
    count_kernel<<<1024, 256, 0, stream>>>(ei, cursor, N, E);
    scanA_kernel<<<nbScan, 1024, 0, stream>>>(cursor, offs, bsum, N);
    scanB_kernel<<<1, 64, 0, stream>>>(bsum, &offs[N], nbScan);
    scanC_kernel<<<nbScan, 1024, 0, stream>>>(offs, cursor, bsum, N);
    fill_kernel<<<1024, 256, 0, stream>>>(ei, cursor, csrc, N, E);

    gemm1_mfma_kernel<<<nbTile, 256, 0, stream>>>(x, W1, a_s1, a_d1, h1, as1, ad1, N);
    msg1_csr_kernel<<<nbWave4, 256, 0, stream>>>(offs, csrc, (const float2*)h1,
        as1, ad1, b1, (float2*)out1, N);
    gemm2_mfma_kernel<<<nbTile, 256, 0, stream>>>(out1, W2, a_s2, a_d2, g2, as2, ad2, N);
    msg2_csr_kernel<<<nbWave4, 256, 0, stream>>>(offs, csrc, (const float2*)g2,
        as2, ad2, b2, (float2*)d_out, N);
}

// Round 12
// 271.995 us; speedup vs baseline: 3.7917x; 1.1868x over previous
//
#include <hip/hip_runtime.h>
#include <hip/hip_bf16.h>

#define C1 128   // heads1(4) * hid(32)
#define C2 64    // out channels layer 2

typedef __attribute__((ext_vector_type(8))) short short8;
typedef __attribute__((ext_vector_type(4))) float floatx4;

__device__ __forceinline__ float lrelu(float v) { return v > 0.f ? v : 0.2f * v; }

// fp32 -> bf16 bits with round-to-nearest-even
__device__ __forceinline__ unsigned short f2bf(float f) {
    unsigned u = __float_as_uint(f);
    u += 0x7FFFu + ((u >> 16) & 1u);
    return (unsigned short)(u >> 16);
}

// ---------------- fused: Layer1 GEMM (MFMA, fp32 I/O) + degree count ----------------
// blocks [0,nbTile): gemm1;  blocks [nbTile, nbTile+1024): count deg
__global__ __launch_bounds__(256)
void g1_count_kernel(const float* __restrict__ x, const float* __restrict__ W1,
                     const float* __restrict__ asrc, const float* __restrict__ adst,
                     unsigned short* __restrict__ h1b,
                     float* __restrict__ as1, float* __restrict__ ad1,
                     int N, int nbTile,
                     const int* __restrict__ ei, int* __restrict__ deg, int E) {
    __shared__ __align__(16) unsigned short Bs[128 * 136];
    if (blockIdx.x >= nbTile) {
        const int b = blockIdx.x - nbTile;
        for (int e = b * 256 + threadIdx.x; e < E; e += 1024 * 256) {
            int d = ei[E + e];
            if ((unsigned)d < (unsigned)N) atomicAdd(&deg[d], 1);
        }
        return;
    }
    // W1 transposed into LDS as bf16: Bs[col][k], stride 136 (2-way banks: free)
    for (int i = threadIdx.x; i < 128 * 64; i += 256) {
        int col = i & 127;
        int k = (i >> 7) * 2;
        unsigned w0 = f2bf(W1[k * 128 + col]);
        unsigned w1 = f2bf(W1[(k + 1) * 128 + col]);
        *(unsigned*)&Bs[col * 136 + k] = w0 | (w1 << 16);
    }
    __syncthreads();

    const int lane = threadIdx.x & 63, ww = threadIdx.x >> 6;
    const int quad = lane >> 4, l16 = lane & 15;
    const int nodeBase = blockIdx.x * 64 + ww * 16;
    int arow = nodeBase + l16;
    if (arow >= N) arow = N - 1;                       // clamp loads; stores guarded
    const float* xp = x + (size_t)arow * C1 + quad * 8;
    short8 afr[4];
#pragma unroll
    for (int kk = 0; kk < 4; ++kk) {
        float4 a0 = *(const float4*)(xp + kk * 32);
        float4 a1 = *(const float4*)(xp + kk * 32 + 4);
        short8 fr;
        fr[0] = (short)f2bf(a0.x); fr[1] = (short)f2bf(a0.y);
        fr[2] = (short)f2bf(a0.z); fr[3] = (short)f2bf(a0.w);
        fr[4] = (short)f2bf(a1.x); fr[5] = (short)f2bf(a1.y);
        fr[6] = (short)f2bf(a1.z); fr[7] = (short)f2bf(a1.w);
        afr[kk] = fr;
    }

    float sacc[4], dacc[4];
#pragma unroll
    for (int ct = 0; ct < 8; ++ct) {
        floatx4 acc = {0.f, 0.f, 0.f, 0.f};
        const int col = ct * 16 + l16;
        const unsigned short* bbase = &Bs[col * 136 + quad * 8];
#pragma unroll
        for (int kk = 0; kk < 4; ++kk) {
            short8 bfr = *(const short8*)(bbase + kk * 32);
            acc = __builtin_amdgcn_mfma_f32_16x16x32_bf16(afr[kk], bfr, acc, 0, 0, 0);
        }
        // C/D layout: col=lane&15, row=quad*4+reg  [m89/m91 verified]
#pragma unroll
        for (int reg = 0; reg < 4; ++reg) {
            int node = nodeBase + quad * 4 + reg;
            if (node < N) h1b[(size_t)node * C1 + col] = f2bf(acc[reg]);
        }
        float av = asrc[col];
        float dv = adst[col];
        if ((ct & 1) == 0) {
#pragma unroll
            for (int r = 0; r < 4; ++r) { sacc[r] = 0.f; dacc[r] = 0.f; }
        }
#pragma unroll
        for (int reg = 0; reg < 4; ++reg) {
            float ts = acc[reg] * av;
            float td = acc[reg] * dv;
#pragma unroll
            for (int o = 1; o < 16; o <<= 1) {
                ts += __shfl_xor(ts, o, 64);
                td += __shfl_xor(td, o, 64);
            }
            sacc[reg] += ts;
            dacc[reg] += td;
        }
        if ((ct & 1) == 1 && l16 == 0) {
            int h = ct >> 1;
#pragma unroll
            for (int reg = 0; reg < 4; ++reg) {
                int node = nodeBase + quad * 4 + reg;
                if (node < N) {
                    as1[node * 4 + h] = sacc[reg];
                    ad1[node * 4 + h] = dacc[reg];
                }
            }
        }
    }
}

// ---------------- scan phase A (proven) ----------------
__global__ __launch_bounds__(1024)
void scanA_kernel(const int* __restrict__ deg, int* __restrict__ offs,
                  int* __restrict__ bsum, int N) {
    __shared__ int wsum[16];
    const int i = blockIdx.x * 1024 + threadIdx.x;
    const int lane = threadIdx.x & 63, wid = threadIdx.x >> 6;
    int v = (i < N) ? deg[i] : 0;
    int x = v;
#pragma unroll
    for (int o = 1; o < 64; o <<= 1) {
        int y = __shfl_up(x, o, 64);
        if (lane >= o) x += y;
    }
    if (lane == 63) wsum[wid] = x;
    __syncthreads();
    if (wid == 0 && lane < 16) {
        int s = wsum[lane];
#pragma unroll
        for (int o = 1; o < 16; o <<= 1) {
            int y = __shfl_up(s, o, 16);
            if (lane >= o) s += y;
        }
        wsum[lane] = s;
    }
    __syncthreads();
    int pre = (wid > 0) ? wsum[wid - 1] : 0;
    int incl = x + pre;
    if (i < N) offs[i] = incl - v;
    if (threadIdx.x == 1023) bsum[blockIdx.x] = incl;
}

// ---------------- scan phase BC fused: redundant top-scan + add prefix ----------------
__global__ __launch_bounds__(1024)
void scanBC_kernel(int* __restrict__ offs, int* __restrict__ cursor,
                   const int* __restrict__ bsum, int N, int nb) {
    __shared__ int pref;
    const int t = threadIdx.x;
    if (t < 64) {
        int v = (t < nb) ? bsum[t] : 0;
        int x = v;
#pragma unroll
        for (int o = 1; o < 64; o <<= 1) {
            int y = __shfl_up(x, o, 64);
            if (t >= o) x += y;
        }
        if (t == (int)blockIdx.x) pref = x - v;       // exclusive prefix of this chunk
        if (blockIdx.x == 0 && t == 63) offs[N] = x;  // grand total
    }
    __syncthreads();
    const int i = blockIdx.x * 1024 + t;
    if (i < N) {
        int o = offs[i] + pref;
        offs[i] = o;
        cursor[i] = o;
    }
}

// ---------------- CSR fill (proven) ----------------
__global__ __launch_bounds__(256)
void fill_kernel(const int* __restrict__ ei, int* __restrict__ cursor,
                 int* __restrict__ csrc, int N, int E) {
    for (int e = blockIdx.x * blockDim.x + threadIdx.x; e < E;
         e += gridDim.x * blockDim.x) {
        int s = ei[e], d = ei[E + e];
        if ((unsigned)s >= (unsigned)N || (unsigned)d >= (unsigned)N) continue;
        int pos = atomicAdd(&cursor[d], 1);
        csrc[pos] = s;
    }
}

// ---------------- Layer 1 CSR gather: proven choreography, bf16-h1 dword gathers ----------------
__global__ __launch_bounds__(256)
void msg1_csr_kernel(const int* __restrict__ offs, const int* __restrict__ csrc,
                     const unsigned* __restrict__ h1u, const float* __restrict__ as1,
                     const float* __restrict__ ad1, const float* __restrict__ b1,
                     float2* __restrict__ out1, int N) {
    const int d = blockIdx.x * 4 + (threadIdx.x >> 6);
    if (d >= N) return;
    const int lane = threadIdx.x & 63;
    const int beg = offs[d], end = offs[d + 1];
    const int k8 = lane & 7;
    const int whead = (lane >> 3) & 3;     // weight-lane head (lanes 0..31)
    const int myHead = lane >> 4;          // consumer head for ch pair (2*lane)
    const float wadh = ad1[d * 4 + whead];
    float accx = 0.f, accy = 0.f, sumw = 0.f;
    for (int jj = beg; jj < end; jj += 8) {
        int idx = jj + k8;
        if (idx >= end) idx = end - 1;
        const int myS = csrc[idx];
        int s[8];
#pragma unroll
        for (int k = 0; k < 8; ++k) s[k] = __shfl(myS, k, 64);
        unsigned rv[8];
#pragma unroll
        for (int k = 0; k < 8; ++k) rv[k] = h1u[(size_t)s[k] * 64 + lane];
        float w = 0.f;
        if (lane < 32 && jj + k8 < end) {
            float a = as1[myS * 4 + whead];
            w = __expf(lrelu(a + wadh));
        }
#pragma unroll
        for (int k = 0; k < 8; ++k) {
            float wk = __shfl(w, myHead * 8 + k, 64);
            sumw += wk;
            accx += wk * __uint_as_float(rv[k] << 16);          // ch 2*lane
            accy += wk * __uint_as_float(rv[k] & 0xFFFF0000u);  // ch 2*lane+1
        }
    }
    float inv = (sumw > 0.f) ? 1.f / sumw : 0.f;
    float rx = accx * inv + b1[2 * lane];
    float ry = accy * inv + b1[2 * lane + 1];
    rx = rx > 0.f ? rx : expm1f(rx);
    ry = ry > 0.f ? ry : expm1f(ry);
    float2 p; p.x = rx; p.y = ry;
    out1[(size_t)d * 64 + lane] = p;
}

// ---------------- Layer 2 GEMM: fp32 in, MFMA bf16 core, bf16 g2 out ----------------
__global__ __launch_bounds__(256)
void gemm2_mfma_kernel(const float* __restrict__ h2, const float* __restrict__ W2,
                       const float* __restrict__ asrc, const float* __restrict__ adst,
                       unsigned short* __restrict__ g2b, float* __restrict__ as2,
                       float* __restrict__ ad2, int N) {
    __shared__ __align__(16) unsigned short Bs[64 * 136];
    for (int i = threadIdx.x; i < 64 * 64; i += 256) {
        int col = i & 63;
        int k = (i >> 6) * 2;
        unsigned w0 = f2bf(W2[k * 64 + col]);
        unsigned w1 = f2bf(W2[(k + 1) * 64 + col]);
        *(unsigned*)&Bs[col * 136 + k] = w0 | (w1 << 16);
    }
    __syncthreads();

    const int lane = threadIdx.x & 63, ww = threadIdx.x >> 6;
    const int quad = lane >> 4, l16 = lane & 15;
    const int nodeBase = blockIdx.x * 64 + ww * 16;
    int arow = nodeBase + l16;
    if (arow >= N) arow = N - 1;
    const float* xp = h2 + (size_t)arow * C1 + quad * 8;
    short8 afr[4];
#pragma unroll
    for (int kk = 0; kk < 4; ++kk) {
        float4 a0 = *(const float4*)(xp + kk * 32);
        float4 a1 = *(const float4*)(xp + kk * 32 + 4);
        short8 fr;
        fr[0] = (short)f2bf(a0.x); fr[1] = (short)f2bf(a0.y);
        fr[2] = (short)f2bf(a0.z); fr[3] = (short)f2bf(a0.w);
        fr[4] = (short)f2bf(a1.x); fr[5] = (short)f2bf(a1.y);
        fr[6] = (short)f2bf(a1.z); fr[7] = (short)f2bf(a1.w);
        afr[kk] = fr;
    }

    float sacc[4] = {0.f,0.f,0.f,0.f}, dacc[4] = {0.f,0.f,0.f,0.f};
#pragma unroll
    for (int ct = 0; ct < 4; ++ct) {
        floatx4 acc = {0.f, 0.f, 0.f, 0.f};
        const int col = ct * 16 + l16;
        const unsigned short* bbase = &Bs[col * 136 + quad * 8];
#pragma unroll
        for (int kk = 0; kk < 4; ++kk) {
            short8 bfr = *(const short8*)(bbase + kk * 32);
            acc = __builtin_amdgcn_mfma_f32_16x16x32_bf16(afr[kk], bfr, acc, 0, 0, 0);
        }
#pragma unroll
        for (int reg = 0; reg < 4; ++reg) {
            int node = nodeBase + quad * 4 + reg;
            if (node < N) g2b[(size_t)node * C2 + col] = f2bf(acc[reg]);
        }
        float av = asrc[col];
        float dv = adst[col];
#pragma unroll
        for (int reg = 0; reg < 4; ++reg) {
            float ts = acc[reg] * av;
            float td = acc[reg] * dv;
#pragma unroll
            for (int o = 1; o < 16; o <<= 1) {
                ts += __shfl_xor(ts, o, 64);
                td += __shfl_xor(td, o, 64);
            }
            sacc[reg] += ts;
            dacc[reg] += td;
        }
    }
    if (l16 == 0) {
#pragma unroll
        for (int reg = 0; reg < 4; ++reg) {
            int node = nodeBase + quad * 4 + reg;
            if (node < N) { as2[node] = sacc[reg]; ad2[node] = dacc[reg]; }
        }
    }
}

// ---------------- Layer 2 CSR gather: proven choreography, bf16-g2 dword gathers ----------------
__global__ __launch_bounds__(256)
void msg2_csr_kernel(const int* __restrict__ offs, const int* __restrict__ csrc,
                     const unsigned* __restrict__ g2u, const float* __restrict__ as2,
                     const float* __restrict__ ad2, const float* __restrict__ b2,
                     float2* __restrict__ y, int N) {
    const int d = blockIdx.x * 4 + (threadIdx.x >> 6);
    if (d >= N) return;
    const int lane = threadIdx.x & 63;
    const int half = lane >> 5;
    const int l32 = lane & 31;
    const int k16 = lane & 15;
    const int beg = offs[d], end = offs[d + 1];
    const float add = ad2[d];
    float accx = 0.f, accy = 0.f, sumw = 0.f;
    for (int jj = beg; jj < end; jj += 16) {
        int idx = jj + k16;
        if (idx >= end) idx = end - 1;
        const int myS = csrc[idx];
        float w = 0.f;
        if (lane < 16 && jj + k16 < end)
            w = __expf(lrelu(as2[myS] + add));
        int s[8];
#pragma unroll
        for (int k = 0; k < 8; ++k) s[k] = __shfl(myS, 2 * k + half, 64);
        unsigned rv[8];
#pragma unroll
        for (int k = 0; k < 8; ++k) rv[k] = g2u[(size_t)s[k] * 32 + l32];
#pragma unroll
        for (int k = 0; k < 8; ++k) {
            float wk = __shfl(w, 2 * k + half, 64);
            sumw += wk;
            accx += wk * __uint_as_float(rv[k] << 16);          // ch 2*l32
            accy += wk * __uint_as_float(rv[k] & 0xFFFF0000u);  // ch 2*l32+1
        }
    }
    accx += __shfl_xor(accx, 32, 64);
    accy += __shfl_xor(accy, 32, 64);
    sumw += __shfl_xor(sumw, 32, 64);
    if (half == 0) {
        float inv = (sumw > 0.f) ? 1.f / sumw : 0.f;
        float2 p;
        p.x = accx * inv + b2[2 * l32];
        p.y = accy * inv + b2[2 * l32 + 1];
        y[(size_t)d * 32 + l32] = p;
    }
}

extern "C" void kernel_launch(void* const* d_in, const int* in_sizes, int n_in,
                              void* d_out, int out_size, void* d_ws, size_t ws_size,
                              hipStream_t stream) {
    const float* x    = (const float*)d_in[0];
    const int*   ei   = (const int*)d_in[1];
    const float* W1   = (const float*)d_in[2];
    const float* a_s1 = (const float*)d_in[3];
    const float* a_d1 = (const float*)d_in[4];
    const float* b1   = (const float*)d_in[5];
    const float* W2   = (const float*)d_in[6];
    const float* a_s2 = (const float*)d_in[7];
    const float* a_d2 = (const float*)d_in[8];
    const float* b2   = (const float*)d_in[9];

    const int N = in_sizes[0] / C1;
    const int E = in_sizes[1] / 2;

    auto align16 = [](size_t v) { return (v + 15) & ~(size_t)15; };
    const size_t RF   = 16;
    const size_t ROFF = align16((size_t)(N + 1) * 4);
    const size_t RCUR = align16((size_t)N * 4);
    const size_t RBS  = 256;
    const size_t RSRC = align16((size_t)E * 4);
    const size_t R1   = align16((size_t)N * C1 * 4);   // h1/g2 region (room kept)
    const size_t R2   = align16((size_t)N * 8 * 4);    // as1+ad1 / as2+ad2

    char* base = (char*)d_ws;
    int*  offs   = (int*)(base + RF);
    int*  cursor = (int*)(base + RF + ROFF);
    int*  bsum   = (int*)(base + RF + ROFF + RCUR);
    int*  csrc   = (int*)(base + RF + ROFF + RCUR + RBS);
    char* R1p = base + RF + ROFF + RCUR + RBS + RSRC;
    char* R2p = R1p + R1;
    char* R4p = R2p + R2;
    (void)ws_size;

    unsigned short* h1 = (unsigned short*)R1p;   // bf16 [N,128]
    unsigned short* g2 = (unsigned short*)R1p;   // bf16 [N,64] (h1 dead after msg1)
    float* as1 = (float*)R2p;
    float* ad1 = as1 + (size_t)N * 4;
    float* as2 = (float*)R2p;                    // as1/ad1 dead after msg1
    float* ad2 = as2 + N;
    float* out1 = (float*)R4p;                   // fp32 [N,128]

    const int nbScan = (N + 1023) / 1024;
    const int nbTile = (N + 63) / 64;
    const int nbWave4 = (N + 3) / 4;

    hipMemsetAsync(cursor, 0, (size_t)N * 4, stream);
    g1_count_kernel<<<nbTile + 1024, 256, 0, stream>>>(x, W1, a_s1, a_d1,
        h1, as1, ad1, N, nbTile, ei, cursor, E);
    scanA_kernel<<<nbScan, 1024, 0, stream>>>(cursor, offs, bsum, N);
    scanBC_kernel<<<nbScan, 1024, 0, stream>>>(offs, cursor, bsum, N, nbScan);
    fill_kernel<<<1024, 256, 0, stream>>>(ei, cursor, csrc, N, E);
    msg1_csr_kernel<<<nbWave4, 256, 0, stream>>>(offs, csrc, (const unsigned*)h1,
        as1, ad1, b1, (float2*)out1, N);
    gemm2_mfma_kernel<<<nbTile, 256, 0, stream>>>(out1, W2, a_s2, a_d2, g2, as2, ad2, N);
    msg2_csr_kernel<<<nbWave4, 256, 0, stream>>>(offs, csrc, (const unsigned*)g2,
        as2, ad2, b2, (float2*)d_out, N);
}

// Round 13
// 255.883 us; speedup vs baseline: 4.0304x; 1.0630x over previous
//
#include <hip/hip_runtime.h>
#include <hip/hip_bf16.h>

#define C1 128   // heads1(4) * hid(32)
#define C2 64    // out channels layer 2

typedef __attribute__((ext_vector_type(8))) short short8;
typedef __attribute__((ext_vector_type(4))) float floatx4;

__device__ __forceinline__ float lrelu(float v) { return v > 0.f ? v : 0.2f * v; }

// fp32 -> bf16 bits with round-to-nearest-even
__device__ __forceinline__ unsigned short f2bf(float f) {
    unsigned u = __float_as_uint(f);
    u += 0x7FFFu + ((u >> 16) & 1u);
    return (unsigned short)(u >> 16);
}

// ---------------- fused: Layer1 GEMM (MFMA, fp32 I/O) + degree count ----------------
// blocks [0,nbTile): gemm1;  blocks [nbTile, nbTile+1024): count deg
__global__ __launch_bounds__(256)
void g1_count_kernel(const float* __restrict__ x, const float* __restrict__ W1,
                     const float* __restrict__ asrc, const float* __restrict__ adst,
                     unsigned short* __restrict__ h1b,
                     float* __restrict__ as1, float* __restrict__ ad1,
                     int N, int nbTile,
                     const int* __restrict__ ei, int* __restrict__ deg, int E) {
    __shared__ __align__(16) unsigned short Bs[128 * 136];
    if (blockIdx.x >= nbTile) {
        const int b = blockIdx.x - nbTile;
        for (int e = b * 256 + threadIdx.x; e < E; e += 1024 * 256) {
            int d = ei[E + e];
            if ((unsigned)d < (unsigned)N) atomicAdd(&deg[d], 1);
        }
        return;
    }
    // W1 transposed into LDS as bf16: Bs[col][k], stride 136 (2-way banks: free)
    for (int i = threadIdx.x; i < 128 * 64; i += 256) {
        int col = i & 127;
        int k = (i >> 7) * 2;
        unsigned w0 = f2bf(W1[k * 128 + col]);
        unsigned w1 = f2bf(W1[(k + 1) * 128 + col]);
        *(unsigned*)&Bs[col * 136 + k] = w0 | (w1 << 16);
    }
    __syncthreads();

    const int lane = threadIdx.x & 63, ww = threadIdx.x >> 6;
    const int quad = lane >> 4, l16 = lane & 15;
    const int nodeBase = blockIdx.x * 64 + ww * 16;
    int arow = nodeBase + l16;
    if (arow >= N) arow = N - 1;                       // clamp loads; stores guarded
    const float* xp = x + (size_t)arow * C1 + quad * 8;
    short8 afr[4];
#pragma unroll
    for (int kk = 0; kk < 4; ++kk) {
        float4 a0 = *(const float4*)(xp + kk * 32);
        float4 a1 = *(const float4*)(xp + kk * 32 + 4);
        short8 fr;
        fr[0] = (short)f2bf(a0.x); fr[1] = (short)f2bf(a0.y);
        fr[2] = (short)f2bf(a0.z); fr[3] = (short)f2bf(a0.w);
        fr[4] = (short)f2bf(a1.x); fr[5] = (short)f2bf(a1.y);
        fr[6] = (short)f2bf(a1.z); fr[7] = (short)f2bf(a1.w);
        afr[kk] = fr;
    }

    float sacc[4], dacc[4];
#pragma unroll
    for (int ct = 0; ct < 8; ++ct) {
        floatx4 acc = {0.f, 0.f, 0.f, 0.f};
        const int col = ct * 16 + l16;
        const unsigned short* bbase = &Bs[col * 136 + quad * 8];
#pragma unroll
        for (int kk = 0; kk < 4; ++kk) {
            short8 bfr = *(const short8*)(bbase + kk * 32);
            acc = __builtin_amdgcn_mfma_f32_16x16x32_bf16(afr[kk], bfr, acc, 0, 0, 0);
        }
        // C/D layout: col=lane&15, row=quad*4+reg  [m89/m91 verified]
#pragma unroll
        for (int reg = 0; reg < 4; ++reg) {
            int node = nodeBase + quad * 4 + reg;
            if (node < N) h1b[(size_t)node * C1 + col] = f2bf(acc[reg]);
        }
        float av = asrc[col];
        float dv = adst[col];
        if ((ct & 1) == 0) {
#pragma unroll
            for (int r = 0; r < 4; ++r) { sacc[r] = 0.f; dacc[r] = 0.f; }
        }
#pragma unroll
        for (int reg = 0; reg < 4; ++reg) {
            float ts = acc[reg] * av;
            float td = acc[reg] * dv;
#pragma unroll
            for (int o = 1; o < 16; o <<= 1) {
                ts += __shfl_xor(ts, o, 64);
                td += __shfl_xor(td, o, 64);
            }
            sacc[reg] += ts;
            dacc[reg] += td;
        }
        if ((ct & 1) == 1 && l16 == 0) {
            int h = ct >> 1;
#pragma unroll
            for (int reg = 0; reg < 4; ++reg) {
                int node = nodeBase + quad * 4 + reg;
                if (node < N) {
                    as1[node * 4 + h] = sacc[reg];
                    ad1[node * 4 + h] = dacc[reg];
                }
            }
        }
    }
}

// ---------------- scan phase A (proven) ----------------
__global__ __launch_bounds__(1024)
void scanA_kernel(const int* __restrict__ deg, int* __restrict__ offs,
                  int* __restrict__ bsum, int N) {
    __shared__ int wsum[16];
    const int i = blockIdx.x * 1024 + threadIdx.x;
    const int lane = threadIdx.x & 63, wid = threadIdx.x >> 6;
    int v = (i < N) ? deg[i] : 0;
    int x = v;
#pragma unroll
    for (int o = 1; o < 64; o <<= 1) {
        int y = __shfl_up(x, o, 64);
        if (lane >= o) x += y;
    }
    if (lane == 63) wsum[wid] = x;
    __syncthreads();
    if (wid == 0 && lane < 16) {
        int s = wsum[lane];
#pragma unroll
        for (int o = 1; o < 16; o <<= 1) {
            int y = __shfl_up(s, o, 16);
            if (lane >= o) s += y;
        }
        wsum[lane] = s;
    }
    __syncthreads();
    int pre = (wid > 0) ? wsum[wid - 1] : 0;
    int incl = x + pre;
    if (i < N) offs[i] = incl - v;
    if (threadIdx.x == 1023) bsum[blockIdx.x] = incl;
}

// ---------------- scan phase BC fused (proven) ----------------
__global__ __launch_bounds__(1024)
void scanBC_kernel(int* __restrict__ offs, int* __restrict__ cursor,
                   const int* __restrict__ bsum, int N, int nb) {
    __shared__ int pref;
    const int t = threadIdx.x;
    if (t < 64) {
        int v = (t < nb) ? bsum[t] : 0;
        int x = v;
#pragma unroll
        for (int o = 1; o < 64; o <<= 1) {
            int y = __shfl_up(x, o, 64);
            if (t >= o) x += y;
        }
        if (t == (int)blockIdx.x) pref = x - v;       // exclusive prefix of this chunk
        if (blockIdx.x == 0 && t == 63) offs[N] = x;  // grand total
    }
    __syncthreads();
    const int i = blockIdx.x * 1024 + t;
    if (i < N) {
        int o = offs[i] + pref;
        offs[i] = o;
        cursor[i] = o;
    }
}

// ---------------- CSR fill, XCD-partitioned ----------------
// Partition k = blockIdx.x % 8 owns dst range [k*N/8, (k+1)*N/8). With the usual
// round-robin block->XCD dispatch, each csrc/cursor region is written by one XCD
// only -> scattered dword stores merge in that XCD's L2 instead of ping-ponging
// partial lines across XCDs (round-12 fill: 53 MB HBM write for 3.2 MB payload).
// Mapping heuristic only affects speed, never correctness.
__global__ __launch_bounds__(256)
void fill_kernel(const int* __restrict__ ei, int* __restrict__ cursor,
                 int* __restrict__ csrc, int N, int E) {
    const int part = blockIdx.x & 7;
    const int bIdx = blockIdx.x >> 3;          // block index within partition
    const int bpp  = gridDim.x >> 3;           // blocks per partition
    const int lo = (int)(((long)N * part) >> 3);
    const int hi = (int)(((long)N * (part + 1)) >> 3);
    for (int e = bIdx * 256 + threadIdx.x; e < E; e += bpp * 256) {
        int d = ei[E + e];
        if (d < lo || d >= hi) continue;       // covers OOB: d<0 or d>=N excluded
        int s = ei[e];
        if ((unsigned)s >= (unsigned)N) continue;
        int pos = atomicAdd(&cursor[d], 1);
        csrc[pos] = s;
    }
}

// ---------------- Layer 1 CSR gather (proven, bf16-h1 dword gathers) ----------------
__global__ __launch_bounds__(256)
void msg1_csr_kernel(const int* __restrict__ offs, const int* __restrict__ csrc,
                     const unsigned* __restrict__ h1u, const float* __restrict__ as1,
                     const float* __restrict__ ad1, const float* __restrict__ b1,
                     float2* __restrict__ out1, int N) {
    const int d = blockIdx.x * 4 + (threadIdx.x >> 6);
    if (d >= N) return;
    const int lane = threadIdx.x & 63;
    const int beg = offs[d], end = offs[d + 1];
    const int k8 = lane & 7;
    const int whead = (lane >> 3) & 3;     // weight-lane head (lanes 0..31)
    const int myHead = lane >> 4;          // consumer head for ch pair (2*lane)
    const float wadh = ad1[d * 4 + whead];
    float accx = 0.f, accy = 0.f, sumw = 0.f;
    for (int jj = beg; jj < end; jj += 8) {
        int idx = jj + k8;
        if (idx >= end) idx = end - 1;
        const int myS = csrc[idx];
        int s[8];
#pragma unroll
        for (int k = 0; k < 8; ++k) s[k] = __shfl(myS, k, 64);
        unsigned rv[8];
#pragma unroll
        for (int k = 0; k < 8; ++k) rv[k] = h1u[(size_t)s[k] * 64 + lane];
        float w = 0.f;
        if (lane < 32 && jj + k8 < end) {
            float a = as1[myS * 4 + whead];
            w = __expf(lrelu(a + wadh));
        }
#pragma unroll
        for (int k = 0; k < 8; ++k) {
            float wk = __shfl(w, myHead * 8 + k, 64);
            sumw += wk;
            accx += wk * __uint_as_float(rv[k] << 16);          // ch 2*lane
            accy += wk * __uint_as_float(rv[k] & 0xFFFF0000u);  // ch 2*lane+1
        }
    }
    float inv = (sumw > 0.f) ? 1.f / sumw : 0.f;
    float rx = accx * inv + b1[2 * lane];
    float ry = accy * inv + b1[2 * lane + 1];
    rx = rx > 0.f ? rx : expm1f(rx);
    ry = ry > 0.f ? ry : expm1f(ry);
    float2 p; p.x = rx; p.y = ry;
    out1[(size_t)d * 64 + lane] = p;
}

// ---------------- Layer 2 GEMM: fp32 in, MFMA bf16 core, bf16 g2 out (proven) ----------------
__global__ __launch_bounds__(256)
void gemm2_mfma_kernel(const float* __restrict__ h2, const float* __restrict__ W2,
                       const float* __restrict__ asrc, const float* __restrict__ adst,
                       unsigned short* __restrict__ g2b, float* __restrict__ as2,
                       float* __restrict__ ad2, int N) {
    __shared__ __align__(16) unsigned short Bs[64 * 136];
    for (int i = threadIdx.x; i < 64 * 64; i += 256) {
        int col = i & 63;
        int k = (i >> 6) * 2;
        unsigned w0 = f2bf(W2[k * 64 + col]);
        unsigned w1 = f2bf(W2[(k + 1) * 64 + col]);
        *(unsigned*)&Bs[col * 136 + k] = w0 | (w1 << 16);
    }
    __syncthreads();

    const int lane = threadIdx.x & 63, ww = threadIdx.x >> 6;
    const int quad = lane >> 4, l16 = lane & 15;
    const int nodeBase = blockIdx.x * 64 + ww * 16;
    int arow = nodeBase + l16;
    if (arow >= N) arow = N - 1;
    const float* xp = h2 + (size_t)arow * C1 + quad * 8;
    short8 afr[4];
#pragma unroll
    for (int kk = 0; kk < 4; ++kk) {
        float4 a0 = *(const float4*)(xp + kk * 32);
        float4 a1 = *(const float4*)(xp + kk * 32 + 4);
        short8 fr;
        fr[0] = (short)f2bf(a0.x); fr[1] = (short)f2bf(a0.y);
        fr[2] = (short)f2bf(a0.z); fr[3] = (short)f2bf(a0.w);
        fr[4] = (short)f2bf(a1.x); fr[5] = (short)f2bf(a1.y);
        fr[6] = (short)f2bf(a1.z); fr[7] = (short)f2bf(a1.w);
        afr[kk] = fr;
    }

    float sacc[4] = {0.f,0.f,0.f,0.f}, dacc[4] = {0.f,0.f,0.f,0.f};
#pragma unroll
    for (int ct = 0; ct < 4; ++ct) {
        floatx4 acc = {0.f, 0.f, 0.f, 0.f};
        const int col = ct * 16 + l16;
        const unsigned short* bbase = &Bs[col * 136 + quad * 8];
#pragma unroll
        for (int kk = 0; kk < 4; ++kk) {
            short8 bfr = *(const short8*)(bbase + kk * 32);
            acc = __builtin_amdgcn_mfma_f32_16x16x32_bf16(afr[kk], bfr, acc, 0, 0, 0);
        }
#pragma unroll
        for (int reg = 0; reg < 4; ++reg) {
            int node = nodeBase + quad * 4 + reg;
            if (node < N) g2b[(size_t)node * C2 + col] = f2bf(acc[reg]);
        }
        float av = asrc[col];
        float dv = adst[col];
#pragma unroll
        for (int reg = 0; reg < 4; ++reg) {
            float ts = acc[reg] * av;
            float td = acc[reg] * dv;
#pragma unroll
            for (int o = 1; o < 16; o <<= 1) {
                ts += __shfl_xor(ts, o, 64);
                td += __shfl_xor(td, o, 64);
            }
            sacc[reg] += ts;
            dacc[reg] += td;
        }
    }
    if (l16 == 0) {
#pragma unroll
        for (int reg = 0; reg < 4; ++reg) {
            int node = nodeBase + quad * 4 + reg;
            if (node < N) { as2[node] = sacc[reg]; ad2[node] = dacc[reg]; }
        }
    }
}

// ---------------- Layer 2 CSR gather (proven, bf16-g2 dword gathers) ----------------
__global__ __launch_bounds__(256)
void msg2_csr_kernel(const int* __restrict__ offs, const int* __restrict__ csrc,
                     const unsigned* __restrict__ g2u, const float* __restrict__ as2,
                     const float* __restrict__ ad2, const float* __restrict__ b2,
                     float2* __restrict__ y, int N) {
    const int d = blockIdx.x * 4 + (threadIdx.x >> 6);
    if (d >= N) return;
    const int lane = threadIdx.x & 63;
    const int half = lane >> 5;
    const int l32 = lane & 31;
    const int k16 = lane & 15;
    const int beg = offs[d], end = offs[d + 1];
    const float add = ad2[d];
    float accx = 0.f, accy = 0.f, sumw = 0.f;
    for (int jj = beg; jj < end; jj += 16) {
        int idx = jj + k16;
        if (idx >= end) idx = end - 1;
        const int myS = csrc[idx];
        float w = 0.f;
        if (lane < 16 && jj + k16 < end)
            w = __expf(lrelu(as2[myS] + add));
        int s[8];
#pragma unroll
        for (int k = 0; k < 8; ++k) s[k] = __shfl(myS, 2 * k + half, 64);
        unsigned rv[8];
#pragma unroll
        for (int k = 0; k < 8; ++k) rv[k] = g2u[(size_t)s[k] * 32 + l32];
#pragma unroll
        for (int k = 0; k < 8; ++k) {
            float wk = __shfl(w, 2 * k + half, 64);
            sumw += wk;
            accx += wk * __uint_as_float(rv[k] << 16);          // ch 2*l32
            accy += wk * __uint_as_float(rv[k] & 0xFFFF0000u);  // ch 2*l32+1
        }
    }
    accx += __shfl_xor(accx, 32, 64);
    accy += __shfl_xor(accy, 32, 64);
    sumw += __shfl_xor(sumw, 32, 64);
    if (half == 0) {
        float inv = (sumw > 0.f) ? 1.f / sumw : 0.f;
        float2 p;
        p.x = accx * inv + b2[2 * l32];
        p.y = accy * inv + b2[2 * l32 + 1];
        y[(size_t)d * 32 + l32] = p;
    }
}

extern "C" void kernel_launch(void* const* d_in, const int* in_sizes, int n_in,
                              void* d_out, int out_size, void* d_ws, size_t ws_size,
                              hipStream_t stream) {
    const float* x    = (const float*)d_in[0];
    const int*   ei   = (const int*)d_in[1];
    const float* W1   = (const float*)d_in[2];
    const float* a_s1 = (const float*)d_in[3];
    const float* a_d1 = (const float*)d_in[4];
    const float* b1   = (const float*)d_in[5];
    const float* W2   = (const float*)d_in[6];
    const float* a_s2 = (const float*)d_in[7];
    const float* a_d2 = (const float*)d_in[8];
    const float* b2   = (const float*)d_in[9];

    const int N = in_sizes[0] / C1;
    const int E = in_sizes[1] / 2;

    auto align16 = [](size_t v) { return (v + 15) & ~(size_t)15; };
    const size_t RF   = 16;
    const size_t ROFF = align16((size_t)(N + 1) * 4);
    const size_t RCUR = align16((size_t)N * 4);
    const size_t RBS  = 256;
    const size_t RSRC = align16((size_t)E * 4);
    const size_t R1   = align16((size_t)N * C1 * 4);   // h1/g2 region (room kept)
    const size_t R2   = align16((size_t)N * 8 * 4);    // as1+ad1 / as2+ad2

    char* base = (char*)d_ws;
    int*  offs   = (int*)(base + RF);
    int*  cursor = (int*)(base + RF + ROFF);
    int*  bsum   = (int*)(base + RF + ROFF + RCUR);
    int*  csrc   = (int*)(base + RF + ROFF + RCUR + RBS);
    char* R1p = base + RF + ROFF + RCUR + RBS + RSRC;
    char* R2p = R1p + R1;
    char* R4p = R2p + R2;
    (void)ws_size;

    unsigned short* h1 = (unsigned short*)R1p;   // bf16 [N,128]
    unsigned short* g2 = (unsigned short*)R1p;   // bf16 [N,64] (h1 dead after msg1)
    float* as1 = (float*)R2p;
    float* ad1 = as1 + (size_t)N * 4;
    float* as2 = (float*)R2p;                    // as1/ad1 dead after msg1
    float* ad2 = as2 + N;
    float* out1 = (float*)R4p;                   // fp32 [N,128]

    const int nbScan = (N + 1023) / 1024;
    const int nbTile = (N + 63) / 64;
    const int nbWave4 = (N + 3) / 4;

    hipMemsetAsync(cursor, 0, (size_t)N * 4, stream);
    g1_count_kernel<<<nbTile + 1024, 256, 0, stream>>>(x, W1, a_s1, a_d1,
        h1, as1, ad1, N, nbTile, ei, cursor, E);
    scanA_kernel<<<nbScan, 1024, 0, stream>>>(cursor, offs, bsum, N);
    scanBC_kernel<<<nbScan, 1024, 0, stream>>>(offs, cursor, bsum, N, nbScan);
    fill_kernel<<<1024, 256, 0, stream>>>(ei, cursor, csrc, N, E);
    msg1_csr_kernel<<<nbWave4, 256, 0, stream>>>(offs, csrc, (const unsigned*)h1,
        as1, ad1, b1, (float2*)out1, N);
    gemm2_mfma_kernel<<<nbTile, 256, 0, stream>>>(out1, W2, a_s2, a_d2, g2, as2, ad2, N);
    msg2_csr_kernel<<<nbWave4, 256, 0, stream>>>(offs, csrc, (const unsigned*)g2,
        as2, ad2, b2, (float2*)d_out, N);
}